// Round 11
// baseline (1515.627 us; speedup 1.0000x reference)
//
#include <hip/hip_runtime.h>
#include <math.h>

// ---------------------------------------------------------------------------
// FeatureEncoder R29 = R28 (1263us) + per-block WEIGHT STAGING IN LDS for
// convT (L4-L6) and conv3s2 (L1-L3).
// Evidence: R27->R28 showed weight-f4 NEUTRAL on convT (160 vs 155) -> the
// weight path's cost is miss latency, not issue count. Weight reads are
// wave-uniform -> scalar loads through the small scalar cache; up to 8
// resident blocks/CU stream DIFFERENT 9-36KB weight slices -> thrash, ~L2
// latency stalls => convT VALUBusy 38%, 62% idle.
// Fix: stage each block's weight slice in LDS in chunks (convT: 64 ic,
// conv3s2: 32 ic; 12KB, rows padded to 12 floats for 16B-aligned float4
// reads). Weight reads become uniform-addr LDS broadcasts (no conflicts,
// guaranteed hits). Two barriers per ~2304-FMA chunk (amortized; not R23's
// per-batch lockstep). Inputs/grids/OCPT/conv7: unchanged R28.
// ---------------------------------------------------------------------------

#define IDIV(a, b) (((a) + (b) - 1) / (b))

__device__ __forceinline__ int reflect_i(int i, int n) {
    i = i < 0 ? -i : i;
    return i >= n ? 2 * n - 2 - i : i;
}

__device__ __forceinline__ float ldb(const char* base, int boff) {
    return *(const float*)(base + boff);
}

// block-level (sum,sumsq) reduction for OCPT channels -> partial store
template <int OCPT>
__device__ __forceinline__ void stats_block_store(
    const float* sv, const float* ssv, float* __restrict__ spart,
    float* __restrict__ sspart, int P, int tile, int pc0) {
    __shared__ float redS[OCPT], redSS[OCPT];
    if (threadIdx.x < OCPT) { redS[threadIdx.x] = 0.f; redSS[threadIdx.x] = 0.f; }
    __syncthreads();
    int lane = threadIdx.x & 63;
#pragma unroll
    for (int j = 0; j < OCPT; ++j) {
        float s = sv[j], ss = ssv[j];
#pragma unroll
        for (int o = 32; o > 0; o >>= 1) {
            s += __shfl_down(s, o);
            ss += __shfl_down(ss, o);
        }
        if (lane == 0) { atomicAdd(&redS[j], s); atomicAdd(&redSS[j], ss); }  // LDS atomics
    }
    __syncthreads();
    if (threadIdx.x < OCPT) {
        spart[(size_t)tile * P + pc0 + threadIdx.x] = redS[threadIdx.x];
        sspart[(size_t)tile * P + pc0 + threadIdx.x] = redSS[threadIdx.x];
    }
}

// fold [nT][P] partials -> mean, inv (one wavefront per plane)
__global__ __launch_bounds__(64) void stat_reduce_mi(
    const float* __restrict__ sp, const float* __restrict__ ssp,
    float* __restrict__ mean, float* __restrict__ inv, int P, int nT,
    float rcp_plane) {
    int p = blockIdx.x;
    float a = 0.f, bsum = 0.f;
    for (int t = threadIdx.x; t < nT; t += 64) {
        a += sp[(size_t)t * P + p];
        bsum += ssp[(size_t)t * P + p];
    }
#pragma unroll
    for (int o = 32; o > 0; o >>= 1) {
        a += __shfl_down(a, o);
        bsum += __shfl_down(bsum, o);
    }
    if (threadIdx.x == 0) {
        float m = a * rcp_plane;
        float var = bsum * rcp_plane - m * m;
        mean[p] = m;
        inv[p] = rsqrtf(var + 1e-5f);
    }
}

// ---------------- 7x7 same-conv (L0), LDS-staged tile, fused stats (R26) ----
template <int CIN, int OCPT>
__global__ __launch_bounds__(256) void conv7_lds(
    const float* __restrict__ x, const float* __restrict__ w,
    const float* __restrict__ b, float* __restrict__ y,
    float* __restrict__ spart, float* __restrict__ sspart, int P,
    int Cout, int H, int W) {
    constexpr int TR = 22, TC = 22, RS = 24;
    __shared__ float s[CIN][TR][RS];
    int tx = threadIdx.x & 15, ty = threadIdx.x >> 4;
    int tilesX = W / 16;
    int bx = blockIdx.x % tilesX, by = blockIdx.x / tilesX;
    int oh0 = by * 16, ow0 = bx * 16;
    int oc0 = blockIdx.y * OCPT;
    int n = blockIdx.z;
    const float* xn = x + (size_t)n * CIN * H * W;

    for (int q = threadIdx.x; q < CIN * TR * TC; q += 256) {
        int p = q / (TR * TC), rem = q % (TR * TC);
        int r = rem / TC, c = rem % TC;
        int ih = reflect_i(oh0 + r - 3, H);
        int iw = reflect_i(ow0 + c - 3, W);
        s[p][r][c] = xn[(size_t)p * H * W + (size_t)ih * W + iw];
    }
    __syncthreads();

    float acc[OCPT];
#pragma unroll
    for (int j = 0; j < OCPT; ++j) acc[j] = 0.f;

    for (int ic = 0; ic < CIN; ++ic) {
        const float* wp = w + ((size_t)oc0 * CIN + ic) * 49;
#pragma unroll
        for (int kh = 0; kh < 7; ++kh) {
#pragma unroll
            for (int kw = 0; kw < 7; ++kw) {
                float vt = s[ic][ty + kh][tx + kw];
#pragma unroll
                for (int j = 0; j < OCPT; ++j)
                    acc[j] += vt * wp[(size_t)j * CIN * 49 + kh * 7 + kw];
            }
        }
    }

    int oh = oh0 + ty, ow = ow0 + tx;
    float sv[OCPT], ssv[OCPT];
#pragma unroll
    for (int j = 0; j < OCPT; ++j) {
        float r = acc[j] + b[oc0 + j];
        y[(((size_t)n * Cout + oc0 + j) * H + oh) * W + ow] = r;
        sv[j] = r;
        ssv[j] = r * r;
    }
    stats_block_store<OCPT>(sv, ssv, spart, sspart, P, blockIdx.x, n * Cout + oc0);
}

// ---------------- 7x7 conv, ic-split partial (L7), LDS-staged (R26) ---------
template <int CINTOT, int ICPB, int OCPT>
__global__ __launch_bounds__(256) void conv7_part_lds(
    const float* __restrict__ x, const float* __restrict__ w,
    float* __restrict__ part, size_t PS, int H, int W) {
    constexpr int TR = 22, TC = 22, RS = 24;
    __shared__ float s[ICPB][TR][RS];
    int tx = threadIdx.x & 15, ty = threadIdx.x >> 4;
    int tilesX = IDIV(W, 16);
    int bx = blockIdx.x % tilesX, by = blockIdx.x / tilesX;
    int oh0 = by * 16, ow0 = bx * 16;
    int ks = blockIdx.y;
    int n = blockIdx.z;
    const int ic0 = ks * ICPB;
    const float* xn = x + (size_t)n * CINTOT * H * W;

    for (int q = threadIdx.x; q < ICPB * TR * TC; q += 256) {
        int p = q / (TR * TC), rem = q % (TR * TC);
        int r = rem / TC, c = rem % TC;
        int ih = reflect_i(oh0 + r - 3, H);
        int iw = reflect_i(ow0 + c - 3, W);
        s[p][r][c] = xn[(size_t)(ic0 + p) * H * W + (size_t)ih * W + iw];
    }
    __syncthreads();

    float acc[OCPT];
#pragma unroll
    for (int j = 0; j < OCPT; ++j) acc[j] = 0.f;

#pragma unroll
    for (int icl = 0; icl < ICPB; ++icl) {
        const float* wp = w + (size_t)(ic0 + icl) * 49;
#pragma unroll
        for (int kh = 0; kh < 7; ++kh) {
#pragma unroll
            for (int kw = 0; kw < 7; ++kw) {
                float vt = s[icl][ty + kh][tx + kw];
#pragma unroll
                for (int j = 0; j < OCPT; ++j)
                    acc[j] += vt * wp[(size_t)j * CINTOT * 49 + kh * 7 + kw];
            }
        }
    }

    int oh = oh0 + ty, ow = ow0 + tx;
    if (oh < H && ow < W) {
#pragma unroll
        for (int j = 0; j < OCPT; ++j)
            part[(size_t)ks * PS + (((size_t)n * OCPT + j) * H + oh) * W + ow] = acc[j];
    }
}

// ---------------- 3x3 s2 conv, f4 input rows + LDS-staged weights -----------
// Weight slice for this block, chunked CHUNK ics at a time, rows padded to
// 12 floats (16B-aligned float4 LDS reads, uniform addr = broadcast).
template <int CIN, int ICB, int OCPT, int CHUNK>
__global__ __launch_bounds__(256) void conv3s2_f4w(
    const float* __restrict__ x, const float* __restrict__ w,
    const float* __restrict__ b, float* __restrict__ y,
    float* __restrict__ spart, float* __restrict__ sspart, int P,
    int Cout, int Hin, int Win, int Hout, int Wout) {
    __shared__ float4 wls[CHUNK * OCPT * 3];
    float* wl = (float*)wls;
    int tx = threadIdx.x & 15, ty = threadIdx.x >> 4;
    int tilesX = Wout >> 4;
    int ow = (blockIdx.x % tilesX) * 16 + tx;
    int oh = (blockIdx.x / tilesX) * 16 + ty;
    int oc0 = blockIdx.y * OCPT;
    int n = blockIdx.z;

    int iw0 = ow * 2 - 1;
    bool shb = iw0 < 0;                 // only ow==0 lanes
    int cb = shb ? 0 : iw0;             // clamped base col, in [0, Win-3]
    int ih0 = oh * 2 - 1;
    int rof[3];
    float mr[3];
#pragma unroll
    for (int kh = 0; kh < 3; ++kh) {
        int ih = ih0 + kh;
        int ihc = min(max(ih, 0), Hin - 1);
        rof[kh] = (ihc * Win + cb) * 4;
        mr[kh] = (ih >= 0 && ih < Hin) ? 1.f : 0.f;
    }

    float acc[OCPT];
#pragma unroll
    for (int j = 0; j < OCPT; ++j) acc[j] = 0.f;

    const char* xb = (const char*)x + (size_t)n * CIN * Hin * Win * 4;
    const int HWb = Hin * Win * 4;

    for (int cc = 0; cc < CIN; cc += CHUNK) {
        __syncthreads();  // protect previous chunk's reads
        // stage weights: (ic in chunk, j, k) -> wl[(ic*OCPT+j)*12 + k]
        for (int q = threadIdx.x; q < CHUNK * OCPT * 9; q += 256) {
            int ic = q / (OCPT * 9);
            int r = q - ic * (OCPT * 9);
            int j = r / 9, k = r - j * 9;
            wl[(ic * OCPT + j) * 12 + k] =
                w[((size_t)(oc0 + j) * CIN + cc + ic) * 9 + k];
        }
        __syncthreads();

        for (int ic0 = cc; ic0 < cc + CHUNK; ic0 += ICB) {
            float t[ICB][9];
#pragma unroll
            for (int icl = 0; icl < ICB; ++icl) {
                const char* xp = xb + (size_t)(ic0 + icl) * HWb;  // uniform
#pragma unroll
                for (int kh = 0; kh < 3; ++kh) {
                    float4 v = *(const float4*)(xp + rof[kh]);
                    float e0 = shb ? 0.f : v.x;
                    float e1 = shb ? v.x : v.y;
                    float e2 = shb ? v.y : v.z;
                    t[icl][kh * 3 + 0] = e0 * mr[kh];
                    t[icl][kh * 3 + 1] = e1 * mr[kh];
                    t[icl][kh * 3 + 2] = e2 * mr[kh];
                }
            }
#pragma unroll
            for (int icl = 0; icl < ICB; ++icl) {
                int wbase = ((ic0 - cc + icl) * OCPT) * 12;
#pragma unroll
                for (int j = 0; j < OCPT; ++j) {
                    const float* wj = wl + wbase + j * 12;
                    float4 wa = *(const float4*)wj;
                    float4 wb = *(const float4*)(wj + 4);
                    float w8 = wj[8];
                    acc[j] += t[icl][0] * wa.x + t[icl][1] * wa.y + t[icl][2] * wa.z +
                              t[icl][3] * wa.w + t[icl][4] * wb.x + t[icl][5] * wb.y +
                              t[icl][6] * wb.z + t[icl][7] * wb.w + t[icl][8] * w8;
                }
            }
        }
    }
    float sv[OCPT], ssv[OCPT];
#pragma unroll
    for (int j = 0; j < OCPT; ++j) {
        float r = acc[j] + b[oc0 + j];
        y[(((size_t)n * Cout + oc0 + j) * Hout + oh) * Wout + ow] = r;
        sv[j] = r;
        ssv[j] = r * r;
    }
    stats_block_store<OCPT>(sv, ssv, spart, sspart, P, blockIdx.x, n * Cout + oc0);
}

// ---------------- 3x3 s2 transposed conv, quad, LDS-staged weights ----------
// torch weight layout w[Cin][Cout][3][3]; output quad at (2qy,2qx).
template <int CIN, int ICB, int OCPT, int CHUNK>
__global__ __launch_bounds__(256) void convt3_v4w(
    const float* __restrict__ x, const float* __restrict__ w,
    const float* __restrict__ b, float* __restrict__ y,
    float* __restrict__ spart, float* __restrict__ sspart, int P,
    int Cout, int Hin, int Win, int Hout, int Wout) {
    __shared__ float4 wls[CHUNK * OCPT * 3];
    float* wl = (float*)wls;
    int tx = threadIdx.x & 15, ty = threadIdx.x >> 4;
    int tilesX = IDIV(Win, 16);
    int qx = (blockIdx.x % tilesX) * 16 + tx;
    int qy = (blockIdx.x / tilesX) * 16 + ty;
    int oc0 = blockIdx.y * OCPT;
    int n = blockIdx.z;
    bool valid = (qx < Win) && (qy < Hin);
    int qxc = min(qx, Win - 1), qyc = min(qy, Hin - 1);
    bool xin = valid && (qx + 1 < Win), yin = valid && (qy + 1 < Hin);
    int o10 = yin ? Win : 0;
    float m01 = xin ? 1.f : 0.f, m10 = yin ? 1.f : 0.f, m11 = m01 * m10;

    int p00 = (qyc * Win + qxc) * 4;
    int p10 = p00 + o10 * 4;

    float a00[OCPT], a01[OCPT], a10[OCPT], a11[OCPT];
#pragma unroll
    for (int j = 0; j < OCPT; ++j) { a00[j] = a01[j] = a10[j] = a11[j] = 0.f; }

    const char* xb = (const char*)x + (size_t)n * CIN * Hin * Win * 4;  // uniform
    const int HWb = Hin * Win * 4;

    float va[ICB][4], vb[ICB][4];
    auto load = [&](float (&v)[ICB][4], int ic0) {
#pragma unroll
        for (int icl = 0; icl < ICB; ++icl) {
            const char* xp = xb + (size_t)(ic0 + icl) * HWb;  // uniform advance
            float2 u = *(const float2*)(xp + p00);
            float2 d = *(const float2*)(xp + p10);
            v[icl][0] = u.x;
            v[icl][1] = u.y * m01;
            v[icl][2] = d.x * m10;
            v[icl][3] = d.y * m11;
        }
    };
    // weights from LDS: row (icl_local*OCPT+j)*12, layout w0..w8 pad3
    auto fma = [&](const float (&v)[ICB][4], int icl0) {
#pragma unroll
        for (int icl = 0; icl < ICB; ++icl) {
            int wbase = ((icl0 + icl) * OCPT) * 12;
#pragma unroll
            for (int j = 0; j < OCPT; ++j) {
                const float* wj = wl + wbase + j * 12;
                float4 wa = *(const float4*)wj;        // w0 w1 w2 w3
                float4 wb = *(const float4*)(wj + 4);  // w4 w5 w6 w7
                float w8 = wj[8];
                a00[j] += wb.x * v[icl][0];
                a01[j] += wb.y * v[icl][0] + wa.w * v[icl][1];
                a10[j] += wb.w * v[icl][0] + wa.y * v[icl][2];
                a11[j] += w8 * v[icl][0] + wb.z * v[icl][1] + wa.z * v[icl][2] +
                          wa.x * v[icl][3];
            }
        }
    };

    for (int cc = 0; cc < CIN; cc += CHUNK) {
        __syncthreads();  // protect previous chunk's reads
        for (int q = threadIdx.x; q < CHUNK * OCPT * 9; q += 256) {
            int ic = q / (OCPT * 9);
            int r = q - ic * (OCPT * 9);
            int j = r / 9, k = r - j * 9;
            wl[(ic * OCPT + j) * 12 + k] =
                w[((size_t)(cc + ic) * Cout + oc0 + j) * 9 + k];
        }
        __syncthreads();

        load(va, cc);
        for (int ic0 = cc; ic0 < cc + CHUNK; ic0 += 2 * ICB) {
            load(vb, ic0 + ICB);
            fma(va, ic0 - cc);
            if (ic0 + 2 * ICB < cc + CHUNK) load(va, ic0 + 2 * ICB);
            fma(vb, ic0 - cc + ICB);
        }
    }

    int oh = 2 * qy, ow = 2 * qx;
    float sv[OCPT], ssv[OCPT];
#pragma unroll
    for (int j = 0; j < OCPT; ++j) {
        float s = 0.f, ss = 0.f;
        if (valid) {
            float bb = b[oc0 + j];
            float* yp = y + (((size_t)n * Cout + oc0 + j) * Hout + oh) * Wout + ow;
            float t00 = a00[j] + bb;
            yp[0] = t00; s += t00; ss += t00 * t00;
            if (xin) { float t = a01[j] + bb; yp[1] = t; s += t; ss += t * t; }
            if (yin) { float t = a10[j] + bb; yp[Wout] = t; s += t; ss += t * t; }
            if (xin && yin) { float t = a11[j] + bb; yp[Wout + 1] = t; s += t; ss += t * t; }
        }
        sv[j] = s; ssv[j] = ss;
    }
    stats_block_store<OCPT>(sv, ssv, spart, sspart, P, blockIdx.x, n * Cout + oc0);
}

// ---------------- inorm apply, float4 coalesced (plane % 4 == 0) ------------
__global__ void inorm_apply4(float* __restrict__ x, const float* __restrict__ mean,
                             const float* __restrict__ inv, int plane4) {
    int pc = blockIdx.y;
    int i = blockIdx.x * 256 + threadIdx.x;
    if (i >= plane4) return;
    float m = mean[pc], iv = inv[pc];
    float4* p = (float4*)(x + (size_t)pc * plane4 * 4);
    float4 v = p[i];
    v.x = fmaxf(0.f, (v.x - m) * iv);
    v.y = fmaxf(0.f, (v.y - m) * iv);
    v.z = fmaxf(0.f, (v.z - m) * iv);
    v.w = fmaxf(0.f, (v.w - m) * iv);
    p[i] = v;
}

// ---------------- inorm apply, 1 elem/thread coalesced (any plane) ----------
__global__ void inorm_apply1(float* __restrict__ x, const float* __restrict__ mean,
                             const float* __restrict__ inv, int plane) {
    int pc = blockIdx.y;
    int i = blockIdx.x * 256 + threadIdx.x;
    if (i >= plane) return;
    float m = mean[pc], iv = inv[pc];
    size_t idx = (size_t)pc * plane + i;
    x[idx] = fmaxf(0.f, (x[idx] - m) * iv);
}

// ---------------- segment mean (accum fused with L7 finalize) ---------------
__global__ void seg_zero(float* __restrict__ bins) {
    if (threadIdx.x < 128) bins[threadIdx.x] = 0.f;
}

// reads the 4 ic-split partials + bias, computes tanh inline; a7 never built.
__global__ void seg_accum_f(const float* __restrict__ part, const float* __restrict__ b,
                            const int* __restrict__ inst, float* __restrict__ bins,
                            int HW, size_t PS) {
    __shared__ float ls[128];  // 96 sums + 32 counts
    for (int i = threadIdx.x; i < 128; i += 256) ls[i] = 0.f;
    __syncthreads();
    int n = blockIdx.y;
    int i = blockIdx.x * 256 + threadIdx.x;
    if (i < HW) {
        int id = inst[(size_t)n * HW + i];
#pragma unroll
        for (int c = 0; c < 3; ++c) {
            size_t off = ((size_t)(n * 3 + c)) * HW + i;
            float v = part[off] + part[PS + off] + part[2 * PS + off] +
                      part[3 * PS + off] + b[c];
            atomicAdd(&ls[id * 3 + c], tanhf(v));
        }
        atomicAdd(&ls[96 + id], 1.0f);
    }
    __syncthreads();
    for (int i2 = threadIdx.x; i2 < 128; i2 += 256)
        if (ls[i2] != 0.f) atomicAdd(&bins[i2], ls[i2]);
}

__global__ void seg_scatter(const float* __restrict__ bins, const int* __restrict__ inst,
                            float* __restrict__ out, int HW) {
    int n = blockIdx.y;
    int i = blockIdx.x * 256 + threadIdx.x;
    if (i >= HW) return;
    int id = inst[(size_t)n * HW + i];
    float c = fmaxf(bins[96 + id], 1.0f);
    out[((size_t)n * 3 + 0) * HW + i] = bins[id * 3 + 0] / c;
    out[((size_t)n * 3 + 1) * HW + i] = bins[id * 3 + 1] / c;
    out[((size_t)n * 3 + 2) * HW + i] = bins[id * 3 + 2] / c;
}

// ---------------------------------------------------------------------------
extern "C" void kernel_launch(void* const* d_in, const int* in_sizes, int n_in,
                              void* d_out, int out_size, void* d_ws, size_t ws_size,
                              hipStream_t stream) {
    const float* x = (const float*)d_in[0];
    const int* inst = (const int*)d_in[1];
    const float* W[8];
    const float* B[8];
    for (int i = 0; i < 8; ++i) {
        W[i] = (const float*)d_in[2 + 2 * i];
        B[i] = (const float*)d_in[3 + 2 * i];
    }
    float* ws = (float*)d_ws;

    // End-aligned ping-pong arena (R2/R6 proven)
    const size_t S = 25165824;  // floats
    float* a0 = ws;                  // [8,32,256,256]
    float* a1 = ws + 16777216;       // [8,64,128,128]
    float* a2 = ws;                  // [8,128,64,64]
    float* a3 = ws + 23068672;       // [8,256,32,32]
    float* a4 = ws;                  // [8,128,63,63]
    float* a5 = ws + 17165824;       // [8,64,125,125]
    float* a6 = ws;                  // [8,32,249,249]  0 .. 15.87M
    float* PART = ws + 16000000;     // 4 x 1488024 floats (gap above a6)
    float* mean = ws + S;            // 2048
    float* inv = mean + 2048;        // 2048
    float* bins = inv + 2048;        // 128
    float* spart = bins + 128;       // 65536 (max nT*P = 256*256)
    float* sspart = spart + 65536;   // 65536

    // L0: 7x7 reflect, 3->32, 256. LDS-staged, OCPT=8, 8192 blocks
    conv7_lds<3, 8><<<dim3(256, 4, 8), 256, 0, stream>>>(
        x, W[0], B[0], a0, spart, sspart, 256, 32, 256, 256);
    stat_reduce_mi<<<dim3(256), 64, 0, stream>>>(spart, sspart, mean, inv, 256, 256, 1.f / 65536.f);
    inorm_apply4<<<dim3(IDIV(16384, 256), 256), 256, 0, stream>>>(a0, mean, inv, 16384);

    // L1: 3x3 s2, 32->64, 256->128. f4 rows + LDS weights, 4096 blocks
    conv3s2_f4w<32, 2, 8, 32><<<dim3(64, 8, 8), 256, 0, stream>>>(
        a0, W[1], B[1], a1, spart, sspart, 512, 64, 256, 256, 128, 128);
    stat_reduce_mi<<<dim3(512), 64, 0, stream>>>(spart, sspart, mean, inv, 512, 64, 1.f / 16384.f);
    inorm_apply4<<<dim3(IDIV(4096, 256), 512), 256, 0, stream>>>(a1, mean, inv, 4096);

    // L2: 3x3 s2, 64->128, 128->64. 2048 blocks
    conv3s2_f4w<64, 2, 8, 32><<<dim3(16, 16, 8), 256, 0, stream>>>(
        a1, W[2], B[2], a2, spart, sspart, 1024, 128, 128, 128, 64, 64);
    stat_reduce_mi<<<dim3(1024), 64, 0, stream>>>(spart, sspart, mean, inv, 1024, 16, 1.f / 4096.f);
    inorm_apply4<<<dim3(IDIV(1024, 256), 1024), 256, 0, stream>>>(a2, mean, inv, 1024);

    // L3: 3x3 s2, 128->256, 64->32. 1024 blocks
    conv3s2_f4w<128, 2, 8, 32><<<dim3(4, 32, 8), 256, 0, stream>>>(
        a2, W[3], B[3], a3, spart, sspart, 2048, 256, 64, 64, 32, 32);
    stat_reduce_mi<<<dim3(2048), 64, 0, stream>>>(spart, sspart, mean, inv, 2048, 4, 1.f / 1024.f);
    inorm_apply4<<<dim3(1, 2048), 256, 0, stream>>>(a3, mean, inv, 256);

    // L4: convT, 256->128, 32->63. f2 inputs + LDS weights, OCPT=4
    convt3_v4w<256, 4, 4, 64><<<dim3(4, 32, 8), 256, 0, stream>>>(
        a3, W[4], B[4], a4, spart, sspart, 1024, 128, 32, 32, 63, 63);
    stat_reduce_mi<<<dim3(1024), 64, 0, stream>>>(spart, sspart, mean, inv, 1024, 4, 1.f / 3969.f);
    inorm_apply1<<<dim3(IDIV(3969, 256), 1024), 256, 0, stream>>>(a4, mean, inv, 3969);

    // L5: convT, 128->64, 63->125. OCPT=4, 2048 blocks
    convt3_v4w<128, 4, 4, 64><<<dim3(16, 16, 8), 256, 0, stream>>>(
        a4, W[5], B[5], a5, spart, sspart, 512, 64, 63, 63, 125, 125);
    stat_reduce_mi<<<dim3(512), 64, 0, stream>>>(spart, sspart, mean, inv, 512, 16, 1.f / 15625.f);
    inorm_apply1<<<dim3(IDIV(15625, 256), 512), 256, 0, stream>>>(a5, mean, inv, 15625);

    // L6: convT, 64->32, 125->249. OCPT=4, 4096 blocks
    convt3_v4w<64, 4, 4, 64><<<dim3(64, 8, 8), 256, 0, stream>>>(
        a5, W[6], B[6], a6, spart, sspart, 256, 32, 125, 125, 249, 249);
    stat_reduce_mi<<<dim3(256), 64, 0, stream>>>(spart, sspart, mean, inv, 256, 64, 1.f / 62001.f);
    inorm_apply1<<<dim3(IDIV(62001, 256), 256), 256, 0, stream>>>(a6, mean, inv, 62001);

    // L7: 7x7 reflect, 32->3, 249 — ic-split x4, LDS-staged
    conv7_part_lds<32, 8, 3><<<dim3(256, 4, 8), 256, 0, stream>>>(
        a6, W[7], PART, 1488024, 249, 249);

    // segment mean (accum reads partials + bias + tanh inline)
    seg_zero<<<1, 128, 0, stream>>>(bins);
    seg_accum_f<<<dim3(IDIV(62001, 256), 8), 256, 0, stream>>>(
        PART, B[7], inst, bins, 62001, 1488024);
    seg_scatter<<<dim3(IDIV(62001, 256), 8), 256, 0, stream>>>(bins, inst, (float*)d_out, 62001);
}

// Round 12
// 1410.006 us; speedup vs baseline: 1.0749x; 1.0749x over previous
//
#include <hip/hip_runtime.h>
#include <math.h>

// ---------------------------------------------------------------------------
// FeatureEncoder R30 = R28 (best, 1263us) + WEIGHT REPACK into contiguous
// per-block streams for conv3s2 (L1-L3) and convT (L4-L6).
// Ledger: weight-f4 (issue count) = neutral; weight-LDS (R29) = regression
// via occupancy. Remaining weight hypothesis: STRIDED GATHER — both kernels
// touch 144B of weights every 4.6KB (convT: per-ic jump = Cout*36B), which
// defeats L2 prefetch + thrashes the 16KB scalar cache (L4 slice = 36KB,
// ~200cyc misses vs 72cyc FMA issue per ic). Fix: launch-start repack to
// [ocblk][ic][j][9] so each block reads its slice SEQUENTIALLY.
// Scratch = d_out (1.49M floats; free until seg_scatter fully overwrites it;
// repacked weights = 774K floats). Compute kernels identical to R28 except
// weight addressing. No VGPR/LDS/grid changes.
// ---------------------------------------------------------------------------

#define IDIV(a, b) (((a) + (b) - 1) / (b))

__device__ __forceinline__ int reflect_i(int i, int n) {
    i = i < 0 ? -i : i;
    return i >= n ? 2 * n - 2 - i : i;
}

__device__ __forceinline__ float ldb(const char* base, int boff) {
    return *(const float*)(base + boff);
}

// ---- weight repack: conv w[Cout][Cin][9] -> r[ocb][ic][j][9] --------------
__global__ void repack_conv(const float* __restrict__ w, float* __restrict__ r,
                            int Cin, int Cout, int OCPT) {
    int i = blockIdx.x * 256 + threadIdx.x;
    int total = Cout * Cin * 9;
    if (i >= total) return;
    int k = i % 9;
    int t = i / 9;
    int ic = t % Cin;
    int oc = t / Cin;
    int ocb = oc / OCPT, j = oc % OCPT;
    r[(((size_t)ocb * Cin + ic) * OCPT + j) * 9 + k] = w[i];
}

// ---- weight repack: convT w[Cin][Cout][9] -> r[ocb][ic][j][9] -------------
__global__ void repack_convT(const float* __restrict__ w, float* __restrict__ r,
                             int Cin, int Cout, int OCPT) {
    int i = blockIdx.x * 256 + threadIdx.x;
    int total = Cin * Cout * 9;
    if (i >= total) return;
    int k = i % 9;
    int t = i / 9;
    int oc = t % Cout;
    int ic = t / Cout;
    int ocb = oc / OCPT, j = oc % OCPT;
    r[(((size_t)ocb * Cin + ic) * OCPT + j) * 9 + k] = w[i];
}

// block-level (sum,sumsq) reduction for OCPT channels -> partial store
template <int OCPT>
__device__ __forceinline__ void stats_block_store(
    const float* sv, const float* ssv, float* __restrict__ spart,
    float* __restrict__ sspart, int P, int tile, int pc0) {
    __shared__ float redS[OCPT], redSS[OCPT];
    if (threadIdx.x < OCPT) { redS[threadIdx.x] = 0.f; redSS[threadIdx.x] = 0.f; }
    __syncthreads();
    int lane = threadIdx.x & 63;
#pragma unroll
    for (int j = 0; j < OCPT; ++j) {
        float s = sv[j], ss = ssv[j];
#pragma unroll
        for (int o = 32; o > 0; o >>= 1) {
            s += __shfl_down(s, o);
            ss += __shfl_down(ss, o);
        }
        if (lane == 0) { atomicAdd(&redS[j], s); atomicAdd(&redSS[j], ss); }  // LDS atomics
    }
    __syncthreads();
    if (threadIdx.x < OCPT) {
        spart[(size_t)tile * P + pc0 + threadIdx.x] = redS[threadIdx.x];
        sspart[(size_t)tile * P + pc0 + threadIdx.x] = redSS[threadIdx.x];
    }
}

// fold [nT][P] partials -> mean, inv (one wavefront per plane)
__global__ __launch_bounds__(64) void stat_reduce_mi(
    const float* __restrict__ sp, const float* __restrict__ ssp,
    float* __restrict__ mean, float* __restrict__ inv, int P, int nT,
    float rcp_plane) {
    int p = blockIdx.x;
    float a = 0.f, bsum = 0.f;
    for (int t = threadIdx.x; t < nT; t += 64) {
        a += sp[(size_t)t * P + p];
        bsum += ssp[(size_t)t * P + p];
    }
#pragma unroll
    for (int o = 32; o > 0; o >>= 1) {
        a += __shfl_down(a, o);
        bsum += __shfl_down(bsum, o);
    }
    if (threadIdx.x == 0) {
        float m = a * rcp_plane;
        float var = bsum * rcp_plane - m * m;
        mean[p] = m;
        inv[p] = rsqrtf(var + 1e-5f);
    }
}

// ---------------- 7x7 same-conv (L0), LDS-staged tile, fused stats (R26) ----
template <int CIN, int OCPT>
__global__ __launch_bounds__(256) void conv7_lds(
    const float* __restrict__ x, const float* __restrict__ w,
    const float* __restrict__ b, float* __restrict__ y,
    float* __restrict__ spart, float* __restrict__ sspart, int P,
    int Cout, int H, int W) {
    constexpr int TR = 22, TC = 22, RS = 24;
    __shared__ float s[CIN][TR][RS];
    int tx = threadIdx.x & 15, ty = threadIdx.x >> 4;
    int tilesX = W / 16;
    int bx = blockIdx.x % tilesX, by = blockIdx.x / tilesX;
    int oh0 = by * 16, ow0 = bx * 16;
    int oc0 = blockIdx.y * OCPT;
    int n = blockIdx.z;
    const float* xn = x + (size_t)n * CIN * H * W;

    for (int q = threadIdx.x; q < CIN * TR * TC; q += 256) {
        int p = q / (TR * TC), rem = q % (TR * TC);
        int r = rem / TC, c = rem % TC;
        int ih = reflect_i(oh0 + r - 3, H);
        int iw = reflect_i(ow0 + c - 3, W);
        s[p][r][c] = xn[(size_t)p * H * W + (size_t)ih * W + iw];
    }
    __syncthreads();

    float acc[OCPT];
#pragma unroll
    for (int j = 0; j < OCPT; ++j) acc[j] = 0.f;

    for (int ic = 0; ic < CIN; ++ic) {
        const float* wp = w + ((size_t)oc0 * CIN + ic) * 49;
#pragma unroll
        for (int kh = 0; kh < 7; ++kh) {
#pragma unroll
            for (int kw = 0; kw < 7; ++kw) {
                float vt = s[ic][ty + kh][tx + kw];
#pragma unroll
                for (int j = 0; j < OCPT; ++j)
                    acc[j] += vt * wp[(size_t)j * CIN * 49 + kh * 7 + kw];
            }
        }
    }

    int oh = oh0 + ty, ow = ow0 + tx;
    float sv[OCPT], ssv[OCPT];
#pragma unroll
    for (int j = 0; j < OCPT; ++j) {
        float r = acc[j] + b[oc0 + j];
        y[(((size_t)n * Cout + oc0 + j) * H + oh) * W + ow] = r;
        sv[j] = r;
        ssv[j] = r * r;
    }
    stats_block_store<OCPT>(sv, ssv, spart, sspart, P, blockIdx.x, n * Cout + oc0);
}

// ---------------- 7x7 conv, ic-split partial (L7), LDS-staged (R26) ---------
template <int CINTOT, int ICPB, int OCPT>
__global__ __launch_bounds__(256) void conv7_part_lds(
    const float* __restrict__ x, const float* __restrict__ w,
    float* __restrict__ part, size_t PS, int H, int W) {
    constexpr int TR = 22, TC = 22, RS = 24;
    __shared__ float s[ICPB][TR][RS];
    int tx = threadIdx.x & 15, ty = threadIdx.x >> 4;
    int tilesX = IDIV(W, 16);
    int bx = blockIdx.x % tilesX, by = blockIdx.x / tilesX;
    int oh0 = by * 16, ow0 = bx * 16;
    int ks = blockIdx.y;
    int n = blockIdx.z;
    const int ic0 = ks * ICPB;
    const float* xn = x + (size_t)n * CINTOT * H * W;

    for (int q = threadIdx.x; q < ICPB * TR * TC; q += 256) {
        int p = q / (TR * TC), rem = q % (TR * TC);
        int r = rem / TC, c = rem % TC;
        int ih = reflect_i(oh0 + r - 3, H);
        int iw = reflect_i(ow0 + c - 3, W);
        s[p][r][c] = xn[(size_t)(ic0 + p) * H * W + (size_t)ih * W + iw];
    }
    __syncthreads();

    float acc[OCPT];
#pragma unroll
    for (int j = 0; j < OCPT; ++j) acc[j] = 0.f;

#pragma unroll
    for (int icl = 0; icl < ICPB; ++icl) {
        const float* wp = w + (size_t)(ic0 + icl) * 49;
#pragma unroll
        for (int kh = 0; kh < 7; ++kh) {
#pragma unroll
            for (int kw = 0; kw < 7; ++kw) {
                float vt = s[icl][ty + kh][tx + kw];
#pragma unroll
                for (int j = 0; j < OCPT; ++j)
                    acc[j] += vt * wp[(size_t)j * CINTOT * 49 + kh * 7 + kw];
            }
        }
    }

    int oh = oh0 + ty, ow = ow0 + tx;
    if (oh < H && ow < W) {
#pragma unroll
        for (int j = 0; j < OCPT; ++j)
            part[(size_t)ks * PS + (((size_t)n * OCPT + j) * H + oh) * W + ow] = acc[j];
    }
}

// ---------------- 3x3 s2 conv, f4 rows + repacked streaming weights ---------
// wr layout: [ocb][ic][j][9]; block's slice = contiguous CIN*OCPT*9 floats.
template <int CIN, int ICB, int OCPT>
__global__ __launch_bounds__(256) void conv3s2_f4r(
    const float* __restrict__ x, const float* __restrict__ wr,
    const float* __restrict__ b, float* __restrict__ y,
    float* __restrict__ spart, float* __restrict__ sspart, int P,
    int Cout, int Hin, int Win, int Hout, int Wout) {
    int tx = threadIdx.x & 15, ty = threadIdx.x >> 4;
    int tilesX = Wout >> 4;
    int ow = (blockIdx.x % tilesX) * 16 + tx;
    int oh = (blockIdx.x / tilesX) * 16 + ty;
    int oc0 = blockIdx.y * OCPT;
    int n = blockIdx.z;
    const float* wblk = wr + (size_t)blockIdx.y * CIN * OCPT * 9;

    int iw0 = ow * 2 - 1;
    bool shb = iw0 < 0;                 // only ow==0 lanes
    int cb = shb ? 0 : iw0;             // clamped base col, in [0, Win-3]
    int ih0 = oh * 2 - 1;
    int rof[3];
    float mr[3];
#pragma unroll
    for (int kh = 0; kh < 3; ++kh) {
        int ih = ih0 + kh;
        int ihc = min(max(ih, 0), Hin - 1);
        rof[kh] = (ihc * Win + cb) * 4;
        mr[kh] = (ih >= 0 && ih < Hin) ? 1.f : 0.f;
    }

    float acc[OCPT];
#pragma unroll
    for (int j = 0; j < OCPT; ++j) acc[j] = 0.f;

    const char* xb = (const char*)x + (size_t)n * CIN * Hin * Win * 4;
    const int HWb = Hin * Win * 4;

    for (int ic0 = 0; ic0 < CIN; ic0 += ICB) {
        float t[ICB][9];
#pragma unroll
        for (int icl = 0; icl < ICB; ++icl) {
            const char* xp = xb + (size_t)(ic0 + icl) * HWb;  // uniform advance
#pragma unroll
            for (int kh = 0; kh < 3; ++kh) {
                float4 v = *(const float4*)(xp + rof[kh]);
                float e0 = shb ? 0.f : v.x;
                float e1 = shb ? v.x : v.y;
                float e2 = shb ? v.y : v.z;
                t[icl][kh * 3 + 0] = e0 * mr[kh];
                t[icl][kh * 3 + 1] = e1 * mr[kh];
                t[icl][kh * 3 + 2] = e2 * mr[kh];
            }
        }
#pragma unroll
        for (int icl = 0; icl < ICB; ++icl) {
            const float* wrow = wblk + ((size_t)(ic0 + icl) * OCPT) * 9;
#pragma unroll
            for (int j = 0; j < OCPT; ++j) {
                const float* wj = wrow + j * 9;
                float4 wa = *(const float4*)wj;
                float4 wb = *(const float4*)(wj + 4);
                float w8 = wj[8];
                acc[j] += t[icl][0] * wa.x + t[icl][1] * wa.y + t[icl][2] * wa.z +
                          t[icl][3] * wa.w + t[icl][4] * wb.x + t[icl][5] * wb.y +
                          t[icl][6] * wb.z + t[icl][7] * wb.w + t[icl][8] * w8;
            }
        }
    }
    float sv[OCPT], ssv[OCPT];
#pragma unroll
    for (int j = 0; j < OCPT; ++j) {
        float r = acc[j] + b[oc0 + j];
        y[(((size_t)n * Cout + oc0 + j) * Hout + oh) * Wout + ow] = r;
        sv[j] = r;
        ssv[j] = r * r;
    }
    stats_block_store<OCPT>(sv, ssv, spart, sspart, P, blockIdx.x, n * Cout + oc0);
}

// ---------------- 3x3 s2 transposed conv, quad, repacked weights ------------
// wr layout: [ocb][ic][j][9]; row = w0..w8 in torch order (flipped use below).
template <int CIN, int ICB, int OCPT>
__global__ __launch_bounds__(256) void convt3_v4r(
    const float* __restrict__ x, const float* __restrict__ wr,
    const float* __restrict__ b, float* __restrict__ y,
    float* __restrict__ spart, float* __restrict__ sspart, int P,
    int Cout, int Hin, int Win, int Hout, int Wout) {
    int tx = threadIdx.x & 15, ty = threadIdx.x >> 4;
    int tilesX = IDIV(Win, 16);
    int qx = (blockIdx.x % tilesX) * 16 + tx;
    int qy = (blockIdx.x / tilesX) * 16 + ty;
    int oc0 = blockIdx.y * OCPT;
    int n = blockIdx.z;
    const float* wblk = wr + (size_t)blockIdx.y * CIN * OCPT * 9;
    bool valid = (qx < Win) && (qy < Hin);
    int qxc = min(qx, Win - 1), qyc = min(qy, Hin - 1);
    bool xin = valid && (qx + 1 < Win), yin = valid && (qy + 1 < Hin);
    int o10 = yin ? Win : 0;
    float m01 = xin ? 1.f : 0.f, m10 = yin ? 1.f : 0.f, m11 = m01 * m10;

    int p00 = (qyc * Win + qxc) * 4;
    int p10 = p00 + o10 * 4;

    float a00[OCPT], a01[OCPT], a10[OCPT], a11[OCPT];
#pragma unroll
    for (int j = 0; j < OCPT; ++j) { a00[j] = a01[j] = a10[j] = a11[j] = 0.f; }

    const char* xb = (const char*)x + (size_t)n * CIN * Hin * Win * 4;  // uniform
    const int HWb = Hin * Win * 4;

    float va[ICB][4], vb[ICB][4];
    auto load = [&](float (&v)[ICB][4], int ic0) {
#pragma unroll
        for (int icl = 0; icl < ICB; ++icl) {
            const char* xp = xb + (size_t)(ic0 + icl) * HWb;  // uniform advance
            float2 u = *(const float2*)(xp + p00);
            float2 d = *(const float2*)(xp + p10);
            v[icl][0] = u.x;
            v[icl][1] = u.y * m01;
            v[icl][2] = d.x * m10;
            v[icl][3] = d.y * m11;
        }
    };
    auto fma = [&](const float (&v)[ICB][4], int ic0) {
#pragma unroll
        for (int icl = 0; icl < ICB; ++icl) {
            const float* wrow = wblk + ((size_t)(ic0 + icl) * OCPT) * 9;
#pragma unroll
            for (int j = 0; j < OCPT; ++j) {
                const float* wj = wrow + j * 9;
                float4 wa = *(const float4*)wj;        // w0 w1 w2 w3
                float4 wb = *(const float4*)(wj + 4);  // w4 w5 w6 w7
                float w8 = wj[8];
                a00[j] += wb.x * v[icl][0];
                a01[j] += wb.y * v[icl][0] + wa.w * v[icl][1];
                a10[j] += wb.w * v[icl][0] + wa.y * v[icl][2];
                a11[j] += w8 * v[icl][0] + wb.z * v[icl][1] + wa.z * v[icl][2] +
                          wa.x * v[icl][3];
            }
        }
    };

    load(va, 0);
    for (int ic0 = 0; ic0 < CIN; ic0 += 2 * ICB) {
        load(vb, ic0 + ICB);
        fma(va, ic0);
        load(va, min(ic0 + 2 * ICB, CIN - ICB));
        fma(vb, ic0 + ICB);
    }

    int oh = 2 * qy, ow = 2 * qx;
    float sv[OCPT], ssv[OCPT];
#pragma unroll
    for (int j = 0; j < OCPT; ++j) {
        float s = 0.f, ss = 0.f;
        if (valid) {
            float bb = b[oc0 + j];
            float* yp = y + (((size_t)n * Cout + oc0 + j) * Hout + oh) * Wout + ow;
            float t00 = a00[j] + bb;
            yp[0] = t00; s += t00; ss += t00 * t00;
            if (xin) { float t = a01[j] + bb; yp[1] = t; s += t; ss += t * t; }
            if (yin) { float t = a10[j] + bb; yp[Wout] = t; s += t; ss += t * t; }
            if (xin && yin) { float t = a11[j] + bb; yp[Wout + 1] = t; s += t; ss += t * t; }
        }
        sv[j] = s; ssv[j] = ss;
    }
    stats_block_store<OCPT>(sv, ssv, spart, sspart, P, blockIdx.x, n * Cout + oc0);
}

// ---------------- inorm apply, float4 coalesced (plane % 4 == 0) ------------
__global__ void inorm_apply4(float* __restrict__ x, const float* __restrict__ mean,
                             const float* __restrict__ inv, int plane4) {
    int pc = blockIdx.y;
    int i = blockIdx.x * 256 + threadIdx.x;
    if (i >= plane4) return;
    float m = mean[pc], iv = inv[pc];
    float4* p = (float4*)(x + (size_t)pc * plane4 * 4);
    float4 v = p[i];
    v.x = fmaxf(0.f, (v.x - m) * iv);
    v.y = fmaxf(0.f, (v.y - m) * iv);
    v.z = fmaxf(0.f, (v.z - m) * iv);
    v.w = fmaxf(0.f, (v.w - m) * iv);
    p[i] = v;
}

// ---------------- inorm apply, 1 elem/thread coalesced (any plane) ----------
__global__ void inorm_apply1(float* __restrict__ x, const float* __restrict__ mean,
                             const float* __restrict__ inv, int plane) {
    int pc = blockIdx.y;
    int i = blockIdx.x * 256 + threadIdx.x;
    if (i >= plane) return;
    float m = mean[pc], iv = inv[pc];
    size_t idx = (size_t)pc * plane + i;
    x[idx] = fmaxf(0.f, (x[idx] - m) * iv);
}

// ---------------- segment mean (accum fused with L7 finalize) ---------------
__global__ void seg_zero(float* __restrict__ bins) {
    if (threadIdx.x < 128) bins[threadIdx.x] = 0.f;
}

// reads the 4 ic-split partials + bias, computes tanh inline; a7 never built.
__global__ void seg_accum_f(const float* __restrict__ part, const float* __restrict__ b,
                            const int* __restrict__ inst, float* __restrict__ bins,
                            int HW, size_t PS) {
    __shared__ float ls[128];  // 96 sums + 32 counts
    for (int i = threadIdx.x; i < 128; i += 256) ls[i] = 0.f;
    __syncthreads();
    int n = blockIdx.y;
    int i = blockIdx.x * 256 + threadIdx.x;
    if (i < HW) {
        int id = inst[(size_t)n * HW + i];
#pragma unroll
        for (int c = 0; c < 3; ++c) {
            size_t off = ((size_t)(n * 3 + c)) * HW + i;
            float v = part[off] + part[PS + off] + part[2 * PS + off] +
                      part[3 * PS + off] + b[c];
            atomicAdd(&ls[id * 3 + c], tanhf(v));
        }
        atomicAdd(&ls[96 + id], 1.0f);
    }
    __syncthreads();
    for (int i2 = threadIdx.x; i2 < 128; i2 += 256)
        if (ls[i2] != 0.f) atomicAdd(&bins[i2], ls[i2]);
}

__global__ void seg_scatter(const float* __restrict__ bins, const int* __restrict__ inst,
                            float* __restrict__ out, int HW) {
    int n = blockIdx.y;
    int i = blockIdx.x * 256 + threadIdx.x;
    if (i >= HW) return;
    int id = inst[(size_t)n * HW + i];
    float c = fmaxf(bins[96 + id], 1.0f);
    out[((size_t)n * 3 + 0) * HW + i] = bins[id * 3 + 0] / c;
    out[((size_t)n * 3 + 1) * HW + i] = bins[id * 3 + 1] / c;
    out[((size_t)n * 3 + 2) * HW + i] = bins[id * 3 + 2] / c;
}

// ---------------------------------------------------------------------------
extern "C" void kernel_launch(void* const* d_in, const int* in_sizes, int n_in,
                              void* d_out, int out_size, void* d_ws, size_t ws_size,
                              hipStream_t stream) {
    const float* x = (const float*)d_in[0];
    const int* inst = (const int*)d_in[1];
    const float* W[8];
    const float* B[8];
    for (int i = 0; i < 8; ++i) {
        W[i] = (const float*)d_in[2 + 2 * i];
        B[i] = (const float*)d_in[3 + 2 * i];
    }
    float* ws = (float*)d_ws;

    // End-aligned ping-pong arena (R2/R6 proven)
    const size_t S = 25165824;  // floats
    float* a0 = ws;                  // [8,32,256,256]
    float* a1 = ws + 16777216;       // [8,64,128,128]
    float* a2 = ws;                  // [8,128,64,64]
    float* a3 = ws + 23068672;       // [8,256,32,32]
    float* a4 = ws;                  // [8,128,63,63]
    float* a5 = ws + 17165824;       // [8,64,125,125]
    float* a6 = ws;                  // [8,32,249,249]  0 .. 15.87M
    float* PART = ws + 16000000;     // 4 x 1488024 floats (gap above a6)
    float* mean = ws + S;            // 2048
    float* inv = mean + 2048;        // 2048
    float* bins = inv + 2048;        // 128
    float* spart = bins + 128;       // 65536 (max nT*P = 256*256)
    float* sspart = spart + 65536;   // 65536

    // Repacked weights live in d_out (free scratch until seg_scatter
    // fully overwrites it). 774144 floats < 1488024 available.
    float* dout = (float*)d_out;
    float* w1r = dout;               // 64*32*9    = 18432
    float* w2r = dout + 18432;       // 128*64*9   = 73728
    float* w3r = dout + 92160;       // 256*128*9  = 294912
    float* w4r = dout + 387072;      // 256..128   = 294912
    float* w5r = dout + 681984;      // 128..64    = 73728
    float* w6r = dout + 755712;      // 64..32     = 18432

    repack_conv<<<IDIV(18432, 256), 256, 0, stream>>>(W[1], w1r, 32, 64, 8);
    repack_conv<<<IDIV(73728, 256), 256, 0, stream>>>(W[2], w2r, 64, 128, 8);
    repack_conv<<<IDIV(294912, 256), 256, 0, stream>>>(W[3], w3r, 128, 256, 8);
    repack_convT<<<IDIV(294912, 256), 256, 0, stream>>>(W[4], w4r, 256, 128, 4);
    repack_convT<<<IDIV(73728, 256), 256, 0, stream>>>(W[5], w5r, 128, 64, 4);
    repack_convT<<<IDIV(18432, 256), 256, 0, stream>>>(W[6], w6r, 64, 32, 4);

    // L0: 7x7 reflect, 3->32, 256. LDS-staged, OCPT=8, 8192 blocks
    conv7_lds<3, 8><<<dim3(256, 4, 8), 256, 0, stream>>>(
        x, W[0], B[0], a0, spart, sspart, 256, 32, 256, 256);
    stat_reduce_mi<<<dim3(256), 64, 0, stream>>>(spart, sspart, mean, inv, 256, 256, 1.f / 65536.f);
    inorm_apply4<<<dim3(IDIV(16384, 256), 256), 256, 0, stream>>>(a0, mean, inv, 16384);

    // L1: 3x3 s2, 32->64, 256->128. f4 rows + repacked weights, 4096 blocks
    conv3s2_f4r<32, 2, 8><<<dim3(64, 8, 8), 256, 0, stream>>>(
        a0, w1r, B[1], a1, spart, sspart, 512, 64, 256, 256, 128, 128);
    stat_reduce_mi<<<dim3(512), 64, 0, stream>>>(spart, sspart, mean, inv, 512, 64, 1.f / 16384.f);
    inorm_apply4<<<dim3(IDIV(4096, 256), 512), 256, 0, stream>>>(a1, mean, inv, 4096);

    // L2: 3x3 s2, 64->128, 128->64. 2048 blocks
    conv3s2_f4r<64, 2, 8><<<dim3(16, 16, 8), 256, 0, stream>>>(
        a1, w2r, B[2], a2, spart, sspart, 1024, 128, 128, 128, 64, 64);
    stat_reduce_mi<<<dim3(1024), 64, 0, stream>>>(spart, sspart, mean, inv, 1024, 16, 1.f / 4096.f);
    inorm_apply4<<<dim3(IDIV(1024, 256), 1024), 256, 0, stream>>>(a2, mean, inv, 1024);

    // L3: 3x3 s2, 128->256, 64->32. 1024 blocks
    conv3s2_f4r<128, 2, 8><<<dim3(4, 32, 8), 256, 0, stream>>>(
        a2, w3r, B[3], a3, spart, sspart, 2048, 256, 64, 64, 32, 32);
    stat_reduce_mi<<<dim3(2048), 64, 0, stream>>>(spart, sspart, mean, inv, 2048, 4, 1.f / 1024.f);
    inorm_apply4<<<dim3(1, 2048), 256, 0, stream>>>(a3, mean, inv, 256);

    // L4: convT, 256->128, 32->63. f2 inputs + repacked weights, OCPT=4
    convt3_v4r<256, 4, 4><<<dim3(4, 32, 8), 256, 0, stream>>>(
        a3, w4r, B[4], a4, spart, sspart, 1024, 128, 32, 32, 63, 63);
    stat_reduce_mi<<<dim3(1024), 64, 0, stream>>>(spart, sspart, mean, inv, 1024, 4, 1.f / 3969.f);
    inorm_apply1<<<dim3(IDIV(3969, 256), 1024), 256, 0, stream>>>(a4, mean, inv, 3969);

    // L5: convT, 128->64, 63->125. OCPT=4, 2048 blocks
    convt3_v4r<128, 4, 4><<<dim3(16, 16, 8), 256, 0, stream>>>(
        a4, w5r, B[5], a5, spart, sspart, 512, 64, 63, 63, 125, 125);
    stat_reduce_mi<<<dim3(512), 64, 0, stream>>>(spart, sspart, mean, inv, 512, 16, 1.f / 15625.f);
    inorm_apply1<<<dim3(IDIV(15625, 256), 512), 256, 0, stream>>>(a5, mean, inv, 15625);

    // L6: convT, 64->32, 125->249. OCPT=4, 4096 blocks
    convt3_v4r<64, 4, 4><<<dim3(64, 8, 8), 256, 0, stream>>>(
        a5, w6r, B[6], a6, spart, sspart, 256, 32, 125, 125, 249, 249);
    stat_reduce_mi<<<dim3(256), 64, 0, stream>>>(spart, sspart, mean, inv, 256, 64, 1.f / 62001.f);
    inorm_apply1<<<dim3(IDIV(62001, 256), 256), 256, 0, stream>>>(a6, mean, inv, 62001);

    // L7: 7x7 reflect, 32->3, 249 — ic-split x4, LDS-staged
    conv7_part_lds<32, 8, 3><<<dim3(256, 4, 8), 256, 0, stream>>>(
        a6, W[7], PART, 1488024, 249, 249);

    // segment mean (accum reads partials + bias + tanh inline)
    seg_zero<<<1, 128, 0, stream>>>(bins);
    seg_accum_f<<<dim3(IDIV(62001, 256), 8), 256, 0, stream>>>(
        PART, B[7], inst, bins, 62001, 1488024);
    seg_scatter<<<dim3(IDIV(62001, 256), 8), 256, 0, stream>>>(bins, inst, (float*)d_out, 62001);
}

// Round 13
// 1258.884 us; speedup vs baseline: 1.2039x; 1.1200x over previous
//
#include <hip/hip_runtime.h>
#include <math.h>

// ---------------------------------------------------------------------------
// FeatureEncoder R31 = EXACT R28 revert (best verified: 1263/1265 us).
// R29 (weight-LDS) and R30 (weight-repack into d_out) both regressed;
// combined with R27/R28's weight-f4 null, the weight path is exonerated:
// W tensors are <=1.2MB, L2-resident, read-only — not the bottleneck.
// Surviving wins: 7x7 LDS input staging (L0/L7, R25), float4 input rows
// (conv3s2, R26), f2 input loads (convT, R26/27). Dead axes (verified):
// OCPT scaling, 2x2 spatial tiles, reg dbuf, stride-2 LDS staging, LDS tap
// vectorization, all three weight-path changes.
// ---------------------------------------------------------------------------

#define IDIV(a, b) (((a) + (b) - 1) / (b))

__device__ __forceinline__ int reflect_i(int i, int n) {
    i = i < 0 ? -i : i;
    return i >= n ? 2 * n - 2 - i : i;
}

__device__ __forceinline__ float ldb(const char* base, int boff) {
    return *(const float*)(base + boff);
}

// block-level (sum,sumsq) reduction for OCPT channels -> partial store
template <int OCPT>
__device__ __forceinline__ void stats_block_store(
    const float* sv, const float* ssv, float* __restrict__ spart,
    float* __restrict__ sspart, int P, int tile, int pc0) {
    __shared__ float redS[OCPT], redSS[OCPT];
    if (threadIdx.x < OCPT) { redS[threadIdx.x] = 0.f; redSS[threadIdx.x] = 0.f; }
    __syncthreads();
    int lane = threadIdx.x & 63;
#pragma unroll
    for (int j = 0; j < OCPT; ++j) {
        float s = sv[j], ss = ssv[j];
#pragma unroll
        for (int o = 32; o > 0; o >>= 1) {
            s += __shfl_down(s, o);
            ss += __shfl_down(ss, o);
        }
        if (lane == 0) { atomicAdd(&redS[j], s); atomicAdd(&redSS[j], ss); }  // LDS atomics
    }
    __syncthreads();
    if (threadIdx.x < OCPT) {
        spart[(size_t)tile * P + pc0 + threadIdx.x] = redS[threadIdx.x];
        sspart[(size_t)tile * P + pc0 + threadIdx.x] = redSS[threadIdx.x];
    }
}

// fold [nT][P] partials -> mean, inv (one wavefront per plane)
__global__ __launch_bounds__(64) void stat_reduce_mi(
    const float* __restrict__ sp, const float* __restrict__ ssp,
    float* __restrict__ mean, float* __restrict__ inv, int P, int nT,
    float rcp_plane) {
    int p = blockIdx.x;
    float a = 0.f, bsum = 0.f;
    for (int t = threadIdx.x; t < nT; t += 64) {
        a += sp[(size_t)t * P + p];
        bsum += ssp[(size_t)t * P + p];
    }
#pragma unroll
    for (int o = 32; o > 0; o >>= 1) {
        a += __shfl_down(a, o);
        bsum += __shfl_down(bsum, o);
    }
    if (threadIdx.x == 0) {
        float m = a * rcp_plane;
        float var = bsum * rcp_plane - m * m;
        mean[p] = m;
        inv[p] = rsqrtf(var + 1e-5f);
    }
}

// ---------------- 7x7 same-conv (L0), LDS-staged tile, fused stats ----------
template <int CIN, int OCPT>
__global__ __launch_bounds__(256) void conv7_lds(
    const float* __restrict__ x, const float* __restrict__ w,
    const float* __restrict__ b, float* __restrict__ y,
    float* __restrict__ spart, float* __restrict__ sspart, int P,
    int Cout, int H, int W) {
    constexpr int TR = 22, TC = 22, RS = 24;
    __shared__ float s[CIN][TR][RS];
    int tx = threadIdx.x & 15, ty = threadIdx.x >> 4;
    int tilesX = W / 16;
    int bx = blockIdx.x % tilesX, by = blockIdx.x / tilesX;
    int oh0 = by * 16, ow0 = bx * 16;
    int oc0 = blockIdx.y * OCPT;
    int n = blockIdx.z;
    const float* xn = x + (size_t)n * CIN * H * W;

    for (int q = threadIdx.x; q < CIN * TR * TC; q += 256) {
        int p = q / (TR * TC), rem = q % (TR * TC);
        int r = rem / TC, c = rem % TC;
        int ih = reflect_i(oh0 + r - 3, H);
        int iw = reflect_i(ow0 + c - 3, W);
        s[p][r][c] = xn[(size_t)p * H * W + (size_t)ih * W + iw];
    }
    __syncthreads();

    float acc[OCPT];
#pragma unroll
    for (int j = 0; j < OCPT; ++j) acc[j] = 0.f;

    for (int ic = 0; ic < CIN; ++ic) {
        const float* wp = w + ((size_t)oc0 * CIN + ic) * 49;
#pragma unroll
        for (int kh = 0; kh < 7; ++kh) {
#pragma unroll
            for (int kw = 0; kw < 7; ++kw) {
                float vt = s[ic][ty + kh][tx + kw];
#pragma unroll
                for (int j = 0; j < OCPT; ++j)
                    acc[j] += vt * wp[(size_t)j * CIN * 49 + kh * 7 + kw];
            }
        }
    }

    int oh = oh0 + ty, ow = ow0 + tx;
    float sv[OCPT], ssv[OCPT];
#pragma unroll
    for (int j = 0; j < OCPT; ++j) {
        float r = acc[j] + b[oc0 + j];
        y[(((size_t)n * Cout + oc0 + j) * H + oh) * W + ow] = r;
        sv[j] = r;
        ssv[j] = r * r;
    }
    stats_block_store<OCPT>(sv, ssv, spart, sspart, P, blockIdx.x, n * Cout + oc0);
}

// ---------------- 7x7 conv, ic-split partial (L7), LDS-staged ---------------
template <int CINTOT, int ICPB, int OCPT>
__global__ __launch_bounds__(256) void conv7_part_lds(
    const float* __restrict__ x, const float* __restrict__ w,
    float* __restrict__ part, size_t PS, int H, int W) {
    constexpr int TR = 22, TC = 22, RS = 24;
    __shared__ float s[ICPB][TR][RS];
    int tx = threadIdx.x & 15, ty = threadIdx.x >> 4;
    int tilesX = IDIV(W, 16);
    int bx = blockIdx.x % tilesX, by = blockIdx.x / tilesX;
    int oh0 = by * 16, ow0 = bx * 16;
    int ks = blockIdx.y;
    int n = blockIdx.z;
    const int ic0 = ks * ICPB;
    const float* xn = x + (size_t)n * CINTOT * H * W;

    for (int q = threadIdx.x; q < ICPB * TR * TC; q += 256) {
        int p = q / (TR * TC), rem = q % (TR * TC);
        int r = rem / TC, c = rem % TC;
        int ih = reflect_i(oh0 + r - 3, H);
        int iw = reflect_i(ow0 + c - 3, W);
        s[p][r][c] = xn[(size_t)(ic0 + p) * H * W + (size_t)ih * W + iw];
    }
    __syncthreads();

    float acc[OCPT];
#pragma unroll
    for (int j = 0; j < OCPT; ++j) acc[j] = 0.f;

#pragma unroll
    for (int icl = 0; icl < ICPB; ++icl) {
        const float* wp = w + (size_t)(ic0 + icl) * 49;
#pragma unroll
        for (int kh = 0; kh < 7; ++kh) {
#pragma unroll
            for (int kw = 0; kw < 7; ++kw) {
                float vt = s[icl][ty + kh][tx + kw];
#pragma unroll
                for (int j = 0; j < OCPT; ++j)
                    acc[j] += vt * wp[(size_t)j * CINTOT * 49 + kh * 7 + kw];
            }
        }
    }

    int oh = oh0 + ty, ow = ow0 + tx;
    if (oh < H && ow < W) {
#pragma unroll
        for (int j = 0; j < OCPT; ++j)
            part[(size_t)ks * PS + (((size_t)n * OCPT + j) * H + oh) * W + ow] = acc[j];
    }
}

// ---------------- 3x3 s2 conv, float4 rows + f4 weights, fused stats --------
template <int CIN, int ICB, int OCPT>
__global__ __launch_bounds__(256) void conv3s2_f4(
    const float* __restrict__ x, const float* __restrict__ w,
    const float* __restrict__ b, float* __restrict__ y,
    float* __restrict__ spart, float* __restrict__ sspart, int P,
    int Cout, int Hin, int Win, int Hout, int Wout) {
    int tx = threadIdx.x & 15, ty = threadIdx.x >> 4;
    int tilesX = Wout >> 4;
    int ow = (blockIdx.x % tilesX) * 16 + tx;
    int oh = (blockIdx.x / tilesX) * 16 + ty;
    int oc0 = blockIdx.y * OCPT;
    int n = blockIdx.z;

    int iw0 = ow * 2 - 1;
    bool shb = iw0 < 0;                 // only ow==0 lanes
    int cb = shb ? 0 : iw0;             // clamped base col, in [0, Win-3]
    int ih0 = oh * 2 - 1;
    int rof[3];
    float mr[3];
#pragma unroll
    for (int kh = 0; kh < 3; ++kh) {
        int ih = ih0 + kh;
        int ihc = min(max(ih, 0), Hin - 1);
        rof[kh] = (ihc * Win + cb) * 4;
        mr[kh] = (ih >= 0 && ih < Hin) ? 1.f : 0.f;
    }

    float acc[OCPT];
#pragma unroll
    for (int j = 0; j < OCPT; ++j) acc[j] = 0.f;

    const char* xb = (const char*)x + (size_t)n * CIN * Hin * Win * 4;
    const int HWb = Hin * Win * 4;

    for (int ic0 = 0; ic0 < CIN; ic0 += ICB) {
        float t[ICB][9];
#pragma unroll
        for (int icl = 0; icl < ICB; ++icl) {
            const char* xp = xb + (size_t)(ic0 + icl) * HWb;  // uniform advance
#pragma unroll
            for (int kh = 0; kh < 3; ++kh) {
                float4 v = *(const float4*)(xp + rof[kh]);
                float e0 = shb ? 0.f : v.x;
                float e1 = shb ? v.x : v.y;
                float e2 = shb ? v.y : v.z;
                t[icl][kh * 3 + 0] = e0 * mr[kh];
                t[icl][kh * 3 + 1] = e1 * mr[kh];
                t[icl][kh * 3 + 2] = e2 * mr[kh];
            }
        }
#pragma unroll
        for (int icl = 0; icl < ICB; ++icl) {
            const float* wp = w + ((size_t)oc0 * CIN + ic0 + icl) * 9;
#pragma unroll
            for (int j = 0; j < OCPT; ++j) {
                const float* wj = wp + (size_t)j * CIN * 9;
                float4 wa = *(const float4*)wj;
                float4 wb = *(const float4*)(wj + 4);
                float w8 = wj[8];
                acc[j] += t[icl][0] * wa.x + t[icl][1] * wa.y + t[icl][2] * wa.z +
                          t[icl][3] * wa.w + t[icl][4] * wb.x + t[icl][5] * wb.y +
                          t[icl][6] * wb.z + t[icl][7] * wb.w + t[icl][8] * w8;
            }
        }
    }
    float sv[OCPT], ssv[OCPT];
#pragma unroll
    for (int j = 0; j < OCPT; ++j) {
        float r = acc[j] + b[oc0 + j];
        y[(((size_t)n * Cout + oc0 + j) * Hout + oh) * Wout + ow] = r;
        sv[j] = r;
        ssv[j] = r * r;
    }
    stats_block_store<OCPT>(sv, ssv, spart, sspart, P, blockIdx.x, n * Cout + oc0);
}

// ---------------- 3x3 s2 transposed conv, quad, f2 inputs, f4 weights -------
// torch weight layout w[Cin][Cout][3][3]; output quad at (2qy,2qx).
template <int CIN, int ICB, int OCPT>
__global__ __launch_bounds__(256) void convt3_v4s(
    const float* __restrict__ x, const float* __restrict__ w,
    const float* __restrict__ b, float* __restrict__ y,
    float* __restrict__ spart, float* __restrict__ sspart, int P,
    int Cout, int Hin, int Win, int Hout, int Wout) {
    int tx = threadIdx.x & 15, ty = threadIdx.x >> 4;
    int tilesX = IDIV(Win, 16);
    int qx = (blockIdx.x % tilesX) * 16 + tx;
    int qy = (blockIdx.x / tilesX) * 16 + ty;
    int oc0 = blockIdx.y * OCPT;
    int n = blockIdx.z;
    bool valid = (qx < Win) && (qy < Hin);
    int qxc = min(qx, Win - 1), qyc = min(qy, Hin - 1);
    bool xin = valid && (qx + 1 < Win), yin = valid && (qy + 1 < Hin);
    int o10 = yin ? Win : 0;
    float m01 = xin ? 1.f : 0.f, m10 = yin ? 1.f : 0.f, m11 = m01 * m10;

    int p00 = (qyc * Win + qxc) * 4;
    int p10 = p00 + o10 * 4;

    float a00[OCPT], a01[OCPT], a10[OCPT], a11[OCPT];
#pragma unroll
    for (int j = 0; j < OCPT; ++j) { a00[j] = a01[j] = a10[j] = a11[j] = 0.f; }

    const char* xb = (const char*)x + (size_t)n * CIN * Hin * Win * 4;  // uniform
    const int HWb = Hin * Win * 4;

    float va[ICB][4], vb[ICB][4];
    auto load = [&](float (&v)[ICB][4], int ic0) {
#pragma unroll
        for (int icl = 0; icl < ICB; ++icl) {
            const char* xp = xb + (size_t)(ic0 + icl) * HWb;  // uniform advance
            float2 u = *(const float2*)(xp + p00);
            float2 d = *(const float2*)(xp + p10);
            v[icl][0] = u.x;
            v[icl][1] = u.y * m01;
            v[icl][2] = d.x * m10;
            v[icl][3] = d.y * m11;
        }
    };
    auto fma = [&](const float (&v)[ICB][4], int ic0) {
#pragma unroll
        for (int icl = 0; icl < ICB; ++icl) {
            const float* wp = w + ((size_t)(ic0 + icl) * Cout + oc0) * 9;
#pragma unroll
            for (int j = 0; j < OCPT; ++j) {
                const float* wj = wp + j * 9;
                float4 wa = *(const float4*)wj;        // w0 w1 w2 w3
                float4 wb = *(const float4*)(wj + 4);  // w4 w5 w6 w7
                float w8 = wj[8];
                a00[j] += wb.x * v[icl][0];
                a01[j] += wb.y * v[icl][0] + wa.w * v[icl][1];
                a10[j] += wb.w * v[icl][0] + wa.y * v[icl][2];
                a11[j] += w8 * v[icl][0] + wb.z * v[icl][1] + wa.z * v[icl][2] +
                          wa.x * v[icl][3];
            }
        }
    };

    load(va, 0);
    for (int ic0 = 0; ic0 < CIN; ic0 += 2 * ICB) {
        load(vb, ic0 + ICB);
        fma(va, ic0);
        load(va, min(ic0 + 2 * ICB, CIN - ICB));
        fma(vb, ic0 + ICB);
    }

    int oh = 2 * qy, ow = 2 * qx;
    float sv[OCPT], ssv[OCPT];
#pragma unroll
    for (int j = 0; j < OCPT; ++j) {
        float s = 0.f, ss = 0.f;
        if (valid) {
            float bb = b[oc0 + j];
            float* yp = y + (((size_t)n * Cout + oc0 + j) * Hout + oh) * Wout + ow;
            float t00 = a00[j] + bb;
            yp[0] = t00; s += t00; ss += t00 * t00;
            if (xin) { float t = a01[j] + bb; yp[1] = t; s += t; ss += t * t; }
            if (yin) { float t = a10[j] + bb; yp[Wout] = t; s += t; ss += t * t; }
            if (xin && yin) { float t = a11[j] + bb; yp[Wout + 1] = t; s += t; ss += t * t; }
        }
        sv[j] = s; ssv[j] = ss;
    }
    stats_block_store<OCPT>(sv, ssv, spart, sspart, P, blockIdx.x, n * Cout + oc0);
}

// ---------------- inorm apply, float4 coalesced (plane % 4 == 0) ------------
__global__ void inorm_apply4(float* __restrict__ x, const float* __restrict__ mean,
                             const float* __restrict__ inv, int plane4) {
    int pc = blockIdx.y;
    int i = blockIdx.x * 256 + threadIdx.x;
    if (i >= plane4) return;
    float m = mean[pc], iv = inv[pc];
    float4* p = (float4*)(x + (size_t)pc * plane4 * 4);
    float4 v = p[i];
    v.x = fmaxf(0.f, (v.x - m) * iv);
    v.y = fmaxf(0.f, (v.y - m) * iv);
    v.z = fmaxf(0.f, (v.z - m) * iv);
    v.w = fmaxf(0.f, (v.w - m) * iv);
    p[i] = v;
}

// ---------------- inorm apply, 1 elem/thread coalesced (any plane) ----------
__global__ void inorm_apply1(float* __restrict__ x, const float* __restrict__ mean,
                             const float* __restrict__ inv, int plane) {
    int pc = blockIdx.y;
    int i = blockIdx.x * 256 + threadIdx.x;
    if (i >= plane) return;
    float m = mean[pc], iv = inv[pc];
    size_t idx = (size_t)pc * plane + i;
    x[idx] = fmaxf(0.f, (x[idx] - m) * iv);
}

// ---------------- segment mean (accum fused with L7 finalize) ---------------
__global__ void seg_zero(float* __restrict__ bins) {
    if (threadIdx.x < 128) bins[threadIdx.x] = 0.f;
}

// reads the 4 ic-split partials + bias, computes tanh inline; a7 never built.
__global__ void seg_accum_f(const float* __restrict__ part, const float* __restrict__ b,
                            const int* __restrict__ inst, float* __restrict__ bins,
                            int HW, size_t PS) {
    __shared__ float ls[128];  // 96 sums + 32 counts
    for (int i = threadIdx.x; i < 128; i += 256) ls[i] = 0.f;
    __syncthreads();
    int n = blockIdx.y;
    int i = blockIdx.x * 256 + threadIdx.x;
    if (i < HW) {
        int id = inst[(size_t)n * HW + i];
#pragma unroll
        for (int c = 0; c < 3; ++c) {
            size_t off = ((size_t)(n * 3 + c)) * HW + i;
            float v = part[off] + part[PS + off] + part[2 * PS + off] +
                      part[3 * PS + off] + b[c];
            atomicAdd(&ls[id * 3 + c], tanhf(v));
        }
        atomicAdd(&ls[96 + id], 1.0f);
    }
    __syncthreads();
    for (int i2 = threadIdx.x; i2 < 128; i2 += 256)
        if (ls[i2] != 0.f) atomicAdd(&bins[i2], ls[i2]);
}

__global__ void seg_scatter(const float* __restrict__ bins, const int* __restrict__ inst,
                            float* __restrict__ out, int HW) {
    int n = blockIdx.y;
    int i = blockIdx.x * 256 + threadIdx.x;
    if (i >= HW) return;
    int id = inst[(size_t)n * HW + i];
    float c = fmaxf(bins[96 + id], 1.0f);
    out[((size_t)n * 3 + 0) * HW + i] = bins[id * 3 + 0] / c;
    out[((size_t)n * 3 + 1) * HW + i] = bins[id * 3 + 1] / c;
    out[((size_t)n * 3 + 2) * HW + i] = bins[id * 3 + 2] / c;
}

// ---------------------------------------------------------------------------
extern "C" void kernel_launch(void* const* d_in, const int* in_sizes, int n_in,
                              void* d_out, int out_size, void* d_ws, size_t ws_size,
                              hipStream_t stream) {
    const float* x = (const float*)d_in[0];
    const int* inst = (const int*)d_in[1];
    const float* W[8];
    const float* B[8];
    for (int i = 0; i < 8; ++i) {
        W[i] = (const float*)d_in[2 + 2 * i];
        B[i] = (const float*)d_in[3 + 2 * i];
    }
    float* ws = (float*)d_ws;

    // End-aligned ping-pong arena (R2/R6 proven)
    const size_t S = 25165824;  // floats
    float* a0 = ws;                  // [8,32,256,256]
    float* a1 = ws + 16777216;       // [8,64,128,128]
    float* a2 = ws;                  // [8,128,64,64]
    float* a3 = ws + 23068672;       // [8,256,32,32]
    float* a4 = ws;                  // [8,128,63,63]
    float* a5 = ws + 17165824;       // [8,64,125,125]
    float* a6 = ws;                  // [8,32,249,249]  0 .. 15.87M
    float* PART = ws + 16000000;     // 4 x 1488024 floats (gap above a6)
    float* mean = ws + S;            // 2048
    float* inv = mean + 2048;        // 2048
    float* bins = inv + 2048;        // 128
    float* spart = bins + 128;       // 65536 (max nT*P = 256*256)
    float* sspart = spart + 65536;   // 65536

    // L0: 7x7 reflect, 3->32, 256. LDS-staged, OCPT=8, 8192 blocks
    conv7_lds<3, 8><<<dim3(256, 4, 8), 256, 0, stream>>>(
        x, W[0], B[0], a0, spart, sspart, 256, 32, 256, 256);
    stat_reduce_mi<<<dim3(256), 64, 0, stream>>>(spart, sspart, mean, inv, 256, 256, 1.f / 65536.f);
    inorm_apply4<<<dim3(IDIV(16384, 256), 256), 256, 0, stream>>>(a0, mean, inv, 16384);

    // L1: 3x3 s2, 32->64, 256->128. float4 rows, ICB=2, OCPT=8, 4096 blocks
    conv3s2_f4<32, 2, 8><<<dim3(64, 8, 8), 256, 0, stream>>>(
        a0, W[1], B[1], a1, spart, sspart, 512, 64, 256, 256, 128, 128);
    stat_reduce_mi<<<dim3(512), 64, 0, stream>>>(spart, sspart, mean, inv, 512, 64, 1.f / 16384.f);
    inorm_apply4<<<dim3(IDIV(4096, 256), 512), 256, 0, stream>>>(a1, mean, inv, 4096);

    // L2: 3x3 s2, 64->128, 128->64. float4 rows, 2048 blocks
    conv3s2_f4<64, 2, 8><<<dim3(16, 16, 8), 256, 0, stream>>>(
        a1, W[2], B[2], a2, spart, sspart, 1024, 128, 128, 128, 64, 64);
    stat_reduce_mi<<<dim3(1024), 64, 0, stream>>>(spart, sspart, mean, inv, 1024, 16, 1.f / 4096.f);
    inorm_apply4<<<dim3(IDIV(1024, 256), 1024), 256, 0, stream>>>(a2, mean, inv, 1024);

    // L3: 3x3 s2, 128->256, 64->32. float4 rows, 1024 blocks
    conv3s2_f4<128, 2, 8><<<dim3(4, 32, 8), 256, 0, stream>>>(
        a2, W[3], B[3], a3, spart, sspart, 2048, 256, 64, 64, 32, 32);
    stat_reduce_mi<<<dim3(2048), 64, 0, stream>>>(spart, sspart, mean, inv, 2048, 4, 1.f / 1024.f);
    inorm_apply4<<<dim3(1, 2048), 256, 0, stream>>>(a3, mean, inv, 256);

    // L4: convT, 256->128, 32->63. f2 inputs + f4 weights, OCPT=4
    convt3_v4s<256, 4, 4><<<dim3(4, 32, 8), 256, 0, stream>>>(
        a3, W[4], B[4], a4, spart, sspart, 1024, 128, 32, 32, 63, 63);
    stat_reduce_mi<<<dim3(1024), 64, 0, stream>>>(spart, sspart, mean, inv, 1024, 4, 1.f / 3969.f);
    inorm_apply1<<<dim3(IDIV(3969, 256), 1024), 256, 0, stream>>>(a4, mean, inv, 3969);

    // L5: convT, 128->64, 63->125. OCPT=4, 2048 blocks
    convt3_v4s<128, 4, 4><<<dim3(16, 16, 8), 256, 0, stream>>>(
        a4, W[5], B[5], a5, spart, sspart, 512, 64, 63, 63, 125, 125);
    stat_reduce_mi<<<dim3(512), 64, 0, stream>>>(spart, sspart, mean, inv, 512, 16, 1.f / 15625.f);
    inorm_apply1<<<dim3(IDIV(15625, 256), 512), 256, 0, stream>>>(a5, mean, inv, 15625);

    // L6: convT, 64->32, 125->249. OCPT=4, 4096 blocks
    convt3_v4s<64, 4, 4><<<dim3(64, 8, 8), 256, 0, stream>>>(
        a5, W[6], B[6], a6, spart, sspart, 256, 32, 125, 125, 249, 249);
    stat_reduce_mi<<<dim3(256), 64, 0, stream>>>(spart, sspart, mean, inv, 256, 64, 1.f / 62001.f);
    inorm_apply1<<<dim3(IDIV(62001, 256), 256), 256, 0, stream>>>(a6, mean, inv, 62001);

    // L7: 7x7 reflect, 32->3, 249 — ic-split x4, LDS-staged
    conv7_part_lds<32, 8, 3><<<dim3(256, 4, 8), 256, 0, stream>>>(
        a6, W[7], PART, 1488024, 249, 249);

    // segment mean (accum reads partials + bias + tanh inline)
    seg_zero<<<1, 128, 0, stream>>>(bins);
    seg_accum_f<<<dim3(IDIV(62001, 256), 8), 256, 0, stream>>>(
        PART, B[7], inst, bins, 62001, 1488024);
    seg_scatter<<<dim3(IDIV(62001, 256), 8), 256, 0, stream>>>(bins, inst, (float*)d_out, 62001);
}

// Round 14
// 1254.387 us; speedup vs baseline: 1.2083x; 1.0036x over previous
//
#include <hip/hip_runtime.h>
#include <math.h>

// ---------------------------------------------------------------------------
// FeatureEncoder R32 = R31 (best, 1259us) + convT weight loads as 9x float4
// per icl (36 contiguous floats for the 4 oc's; 16B-aligned since oc0%4==0
// and Cout%4==0). VMEM per icl: 14 -> 11 (-21%).
// Theory: convT time is independent of occupancy (L4@4blk/CU == L6@16blk/CU
// == 157us) -> TLP not limiting; VMEM issue/TA throughput is (3584 VMEM vs
// 9216 FMA per thread, ~14k vs 18k cycles). Cut VMEM count, nothing else.
// All other kernels byte-identical to R31.
// ---------------------------------------------------------------------------

#define IDIV(a, b) (((a) + (b) - 1) / (b))

__device__ __forceinline__ int reflect_i(int i, int n) {
    i = i < 0 ? -i : i;
    return i >= n ? 2 * n - 2 - i : i;
}

__device__ __forceinline__ float ldb(const char* base, int boff) {
    return *(const float*)(base + boff);
}

// block-level (sum,sumsq) reduction for OCPT channels -> partial store
template <int OCPT>
__device__ __forceinline__ void stats_block_store(
    const float* sv, const float* ssv, float* __restrict__ spart,
    float* __restrict__ sspart, int P, int tile, int pc0) {
    __shared__ float redS[OCPT], redSS[OCPT];
    if (threadIdx.x < OCPT) { redS[threadIdx.x] = 0.f; redSS[threadIdx.x] = 0.f; }
    __syncthreads();
    int lane = threadIdx.x & 63;
#pragma unroll
    for (int j = 0; j < OCPT; ++j) {
        float s = sv[j], ss = ssv[j];
#pragma unroll
        for (int o = 32; o > 0; o >>= 1) {
            s += __shfl_down(s, o);
            ss += __shfl_down(ss, o);
        }
        if (lane == 0) { atomicAdd(&redS[j], s); atomicAdd(&redSS[j], ss); }  // LDS atomics
    }
    __syncthreads();
    if (threadIdx.x < OCPT) {
        spart[(size_t)tile * P + pc0 + threadIdx.x] = redS[threadIdx.x];
        sspart[(size_t)tile * P + pc0 + threadIdx.x] = redSS[threadIdx.x];
    }
}

// fold [nT][P] partials -> mean, inv (one wavefront per plane)
__global__ __launch_bounds__(64) void stat_reduce_mi(
    const float* __restrict__ sp, const float* __restrict__ ssp,
    float* __restrict__ mean, float* __restrict__ inv, int P, int nT,
    float rcp_plane) {
    int p = blockIdx.x;
    float a = 0.f, bsum = 0.f;
    for (int t = threadIdx.x; t < nT; t += 64) {
        a += sp[(size_t)t * P + p];
        bsum += ssp[(size_t)t * P + p];
    }
#pragma unroll
    for (int o = 32; o > 0; o >>= 1) {
        a += __shfl_down(a, o);
        bsum += __shfl_down(bsum, o);
    }
    if (threadIdx.x == 0) {
        float m = a * rcp_plane;
        float var = bsum * rcp_plane - m * m;
        mean[p] = m;
        inv[p] = rsqrtf(var + 1e-5f);
    }
}

// ---------------- 7x7 same-conv (L0), LDS-staged tile, fused stats ----------
template <int CIN, int OCPT>
__global__ __launch_bounds__(256) void conv7_lds(
    const float* __restrict__ x, const float* __restrict__ w,
    const float* __restrict__ b, float* __restrict__ y,
    float* __restrict__ spart, float* __restrict__ sspart, int P,
    int Cout, int H, int W) {
    constexpr int TR = 22, TC = 22, RS = 24;
    __shared__ float s[CIN][TR][RS];
    int tx = threadIdx.x & 15, ty = threadIdx.x >> 4;
    int tilesX = W / 16;
    int bx = blockIdx.x % tilesX, by = blockIdx.x / tilesX;
    int oh0 = by * 16, ow0 = bx * 16;
    int oc0 = blockIdx.y * OCPT;
    int n = blockIdx.z;
    const float* xn = x + (size_t)n * CIN * H * W;

    for (int q = threadIdx.x; q < CIN * TR * TC; q += 256) {
        int p = q / (TR * TC), rem = q % (TR * TC);
        int r = rem / TC, c = rem % TC;
        int ih = reflect_i(oh0 + r - 3, H);
        int iw = reflect_i(ow0 + c - 3, W);
        s[p][r][c] = xn[(size_t)p * H * W + (size_t)ih * W + iw];
    }
    __syncthreads();

    float acc[OCPT];
#pragma unroll
    for (int j = 0; j < OCPT; ++j) acc[j] = 0.f;

    for (int ic = 0; ic < CIN; ++ic) {
        const float* wp = w + ((size_t)oc0 * CIN + ic) * 49;
#pragma unroll
        for (int kh = 0; kh < 7; ++kh) {
#pragma unroll
            for (int kw = 0; kw < 7; ++kw) {
                float vt = s[ic][ty + kh][tx + kw];
#pragma unroll
                for (int j = 0; j < OCPT; ++j)
                    acc[j] += vt * wp[(size_t)j * CIN * 49 + kh * 7 + kw];
            }
        }
    }

    int oh = oh0 + ty, ow = ow0 + tx;
    float sv[OCPT], ssv[OCPT];
#pragma unroll
    for (int j = 0; j < OCPT; ++j) {
        float r = acc[j] + b[oc0 + j];
        y[(((size_t)n * Cout + oc0 + j) * H + oh) * W + ow] = r;
        sv[j] = r;
        ssv[j] = r * r;
    }
    stats_block_store<OCPT>(sv, ssv, spart, sspart, P, blockIdx.x, n * Cout + oc0);
}

// ---------------- 7x7 conv, ic-split partial (L7), LDS-staged ---------------
template <int CINTOT, int ICPB, int OCPT>
__global__ __launch_bounds__(256) void conv7_part_lds(
    const float* __restrict__ x, const float* __restrict__ w,
    float* __restrict__ part, size_t PS, int H, int W) {
    constexpr int TR = 22, TC = 22, RS = 24;
    __shared__ float s[ICPB][TR][RS];
    int tx = threadIdx.x & 15, ty = threadIdx.x >> 4;
    int tilesX = IDIV(W, 16);
    int bx = blockIdx.x % tilesX, by = blockIdx.x / tilesX;
    int oh0 = by * 16, ow0 = bx * 16;
    int ks = blockIdx.y;
    int n = blockIdx.z;
    const int ic0 = ks * ICPB;
    const float* xn = x + (size_t)n * CINTOT * H * W;

    for (int q = threadIdx.x; q < ICPB * TR * TC; q += 256) {
        int p = q / (TR * TC), rem = q % (TR * TC);
        int r = rem / TC, c = rem % TC;
        int ih = reflect_i(oh0 + r - 3, H);
        int iw = reflect_i(ow0 + c - 3, W);
        s[p][r][c] = xn[(size_t)(ic0 + p) * H * W + (size_t)ih * W + iw];
    }
    __syncthreads();

    float acc[OCPT];
#pragma unroll
    for (int j = 0; j < OCPT; ++j) acc[j] = 0.f;

#pragma unroll
    for (int icl = 0; icl < ICPB; ++icl) {
        const float* wp = w + (size_t)(ic0 + icl) * 49;
#pragma unroll
        for (int kh = 0; kh < 7; ++kh) {
#pragma unroll
            for (int kw = 0; kw < 7; ++kw) {
                float vt = s[icl][ty + kh][tx + kw];
#pragma unroll
                for (int j = 0; j < OCPT; ++j)
                    acc[j] += vt * wp[(size_t)j * CINTOT * 49 + kh * 7 + kw];
            }
        }
    }

    int oh = oh0 + ty, ow = ow0 + tx;
    if (oh < H && ow < W) {
#pragma unroll
        for (int j = 0; j < OCPT; ++j)
            part[(size_t)ks * PS + (((size_t)n * OCPT + j) * H + oh) * W + ow] = acc[j];
    }
}

// ---------------- 3x3 s2 conv, float4 rows + f4 weights, fused stats --------
template <int CIN, int ICB, int OCPT>
__global__ __launch_bounds__(256) void conv3s2_f4(
    const float* __restrict__ x, const float* __restrict__ w,
    const float* __restrict__ b, float* __restrict__ y,
    float* __restrict__ spart, float* __restrict__ sspart, int P,
    int Cout, int Hin, int Win, int Hout, int Wout) {
    int tx = threadIdx.x & 15, ty = threadIdx.x >> 4;
    int tilesX = Wout >> 4;
    int ow = (blockIdx.x % tilesX) * 16 + tx;
    int oh = (blockIdx.x / tilesX) * 16 + ty;
    int oc0 = blockIdx.y * OCPT;
    int n = blockIdx.z;

    int iw0 = ow * 2 - 1;
    bool shb = iw0 < 0;                 // only ow==0 lanes
    int cb = shb ? 0 : iw0;             // clamped base col, in [0, Win-3]
    int ih0 = oh * 2 - 1;
    int rof[3];
    float mr[3];
#pragma unroll
    for (int kh = 0; kh < 3; ++kh) {
        int ih = ih0 + kh;
        int ihc = min(max(ih, 0), Hin - 1);
        rof[kh] = (ihc * Win + cb) * 4;
        mr[kh] = (ih >= 0 && ih < Hin) ? 1.f : 0.f;
    }

    float acc[OCPT];
#pragma unroll
    for (int j = 0; j < OCPT; ++j) acc[j] = 0.f;

    const char* xb = (const char*)x + (size_t)n * CIN * Hin * Win * 4;
    const int HWb = Hin * Win * 4;

    for (int ic0 = 0; ic0 < CIN; ic0 += ICB) {
        float t[ICB][9];
#pragma unroll
        for (int icl = 0; icl < ICB; ++icl) {
            const char* xp = xb + (size_t)(ic0 + icl) * HWb;  // uniform advance
#pragma unroll
            for (int kh = 0; kh < 3; ++kh) {
                float4 v = *(const float4*)(xp + rof[kh]);
                float e0 = shb ? 0.f : v.x;
                float e1 = shb ? v.x : v.y;
                float e2 = shb ? v.y : v.z;
                t[icl][kh * 3 + 0] = e0 * mr[kh];
                t[icl][kh * 3 + 1] = e1 * mr[kh];
                t[icl][kh * 3 + 2] = e2 * mr[kh];
            }
        }
#pragma unroll
        for (int icl = 0; icl < ICB; ++icl) {
            const float* wp = w + ((size_t)oc0 * CIN + ic0 + icl) * 9;
#pragma unroll
            for (int j = 0; j < OCPT; ++j) {
                const float* wj = wp + (size_t)j * CIN * 9;
                float4 wa = *(const float4*)wj;
                float4 wb = *(const float4*)(wj + 4);
                float w8 = wj[8];
                acc[j] += t[icl][0] * wa.x + t[icl][1] * wa.y + t[icl][2] * wa.z +
                          t[icl][3] * wa.w + t[icl][4] * wb.x + t[icl][5] * wb.y +
                          t[icl][6] * wb.z + t[icl][7] * wb.w + t[icl][8] * w8;
            }
        }
    }
    float sv[OCPT], ssv[OCPT];
#pragma unroll
    for (int j = 0; j < OCPT; ++j) {
        float r = acc[j] + b[oc0 + j];
        y[(((size_t)n * Cout + oc0 + j) * Hout + oh) * Wout + ow] = r;
        sv[j] = r;
        ssv[j] = r * r;
    }
    stats_block_store<OCPT>(sv, ssv, spart, sspart, P, blockIdx.x, n * Cout + oc0);
}

// ---------------- 3x3 s2 transposed conv, quad, f2 inputs, 9xf4 weights -----
// torch weight layout w[Cin][Cout][3][3]; output quad at (2qy,2qx).
// For fixed ic, the OCPT=4 oc's weights are 36 CONTIGUOUS floats (oc stride
// = 9), 16B-aligned (oc0%4==0, Cout%4==0) -> 9 float4 loads (was 12).
template <int CIN, int ICB, int OCPT>
__global__ __launch_bounds__(256) void convt3_v4s(
    const float* __restrict__ x, const float* __restrict__ w,
    const float* __restrict__ b, float* __restrict__ y,
    float* __restrict__ spart, float* __restrict__ sspart, int P,
    int Cout, int Hin, int Win, int Hout, int Wout) {
    static_assert(OCPT == 4, "9xf4 weight path assumes OCPT==4");
    int tx = threadIdx.x & 15, ty = threadIdx.x >> 4;
    int tilesX = IDIV(Win, 16);
    int qx = (blockIdx.x % tilesX) * 16 + tx;
    int qy = (blockIdx.x / tilesX) * 16 + ty;
    int oc0 = blockIdx.y * OCPT;
    int n = blockIdx.z;
    bool valid = (qx < Win) && (qy < Hin);
    int qxc = min(qx, Win - 1), qyc = min(qy, Hin - 1);
    bool xin = valid && (qx + 1 < Win), yin = valid && (qy + 1 < Hin);
    int o10 = yin ? Win : 0;
    float m01 = xin ? 1.f : 0.f, m10 = yin ? 1.f : 0.f, m11 = m01 * m10;

    int p00 = (qyc * Win + qxc) * 4;
    int p10 = p00 + o10 * 4;

    float a00[OCPT], a01[OCPT], a10[OCPT], a11[OCPT];
#pragma unroll
    for (int j = 0; j < OCPT; ++j) { a00[j] = a01[j] = a10[j] = a11[j] = 0.f; }

    const char* xb = (const char*)x + (size_t)n * CIN * Hin * Win * 4;  // uniform
    const int HWb = Hin * Win * 4;

    float va[ICB][4], vb[ICB][4];
    auto load = [&](float (&v)[ICB][4], int ic0) {
#pragma unroll
        for (int icl = 0; icl < ICB; ++icl) {
            const char* xp = xb + (size_t)(ic0 + icl) * HWb;  // uniform advance
            float2 u = *(const float2*)(xp + p00);
            float2 d = *(const float2*)(xp + p10);
            v[icl][0] = u.x;
            v[icl][1] = u.y * m01;
            v[icl][2] = d.x * m10;
            v[icl][3] = d.y * m11;
        }
    };
    auto fma = [&](const float (&v)[ICB][4], int ic0) {
#pragma unroll
        for (int icl = 0; icl < ICB; ++icl) {
            const float* wp = w + ((size_t)(ic0 + icl) * Cout + oc0) * 9;
            float4 q[9];
#pragma unroll
            for (int c = 0; c < 9; ++c) q[c] = *(const float4*)(wp + 4 * c);
            const float* wf = (const float*)q;   // 36 floats, const-indexed
#pragma unroll
            for (int j = 0; j < OCPT; ++j) {
                float w0 = wf[j * 9 + 0], w1 = wf[j * 9 + 1], w2 = wf[j * 9 + 2];
                float w3 = wf[j * 9 + 3], w4 = wf[j * 9 + 4], w5 = wf[j * 9 + 5];
                float w6 = wf[j * 9 + 6], w7 = wf[j * 9 + 7], w8 = wf[j * 9 + 8];
                a00[j] += w4 * v[icl][0];
                a01[j] += w5 * v[icl][0] + w3 * v[icl][1];
                a10[j] += w7 * v[icl][0] + w1 * v[icl][2];
                a11[j] += w8 * v[icl][0] + w6 * v[icl][1] + w2 * v[icl][2] +
                          w0 * v[icl][3];
            }
        }
    };

    load(va, 0);
    for (int ic0 = 0; ic0 < CIN; ic0 += 2 * ICB) {
        load(vb, ic0 + ICB);
        fma(va, ic0);
        load(va, min(ic0 + 2 * ICB, CIN - ICB));
        fma(vb, ic0 + ICB);
    }

    int oh = 2 * qy, ow = 2 * qx;
    float sv[OCPT], ssv[OCPT];
#pragma unroll
    for (int j = 0; j < OCPT; ++j) {
        float s = 0.f, ss = 0.f;
        if (valid) {
            float bb = b[oc0 + j];
            float* yp = y + (((size_t)n * Cout + oc0 + j) * Hout + oh) * Wout + ow;
            float t00 = a00[j] + bb;
            yp[0] = t00; s += t00; ss += t00 * t00;
            if (xin) { float t = a01[j] + bb; yp[1] = t; s += t; ss += t * t; }
            if (yin) { float t = a10[j] + bb; yp[Wout] = t; s += t; ss += t * t; }
            if (xin && yin) { float t = a11[j] + bb; yp[Wout + 1] = t; s += t; ss += t * t; }
        }
        sv[j] = s; ssv[j] = ss;
    }
    stats_block_store<OCPT>(sv, ssv, spart, sspart, P, blockIdx.x, n * Cout + oc0);
}

// ---------------- inorm apply, float4 coalesced (plane % 4 == 0) ------------
__global__ void inorm_apply4(float* __restrict__ x, const float* __restrict__ mean,
                             const float* __restrict__ inv, int plane4) {
    int pc = blockIdx.y;
    int i = blockIdx.x * 256 + threadIdx.x;
    if (i >= plane4) return;
    float m = mean[pc], iv = inv[pc];
    float4* p = (float4*)(x + (size_t)pc * plane4 * 4);
    float4 v = p[i];
    v.x = fmaxf(0.f, (v.x - m) * iv);
    v.y = fmaxf(0.f, (v.y - m) * iv);
    v.z = fmaxf(0.f, (v.z - m) * iv);
    v.w = fmaxf(0.f, (v.w - m) * iv);
    p[i] = v;
}

// ---------------- inorm apply, 1 elem/thread coalesced (any plane) ----------
__global__ void inorm_apply1(float* __restrict__ x, const float* __restrict__ mean,
                             const float* __restrict__ inv, int plane) {
    int pc = blockIdx.y;
    int i = blockIdx.x * 256 + threadIdx.x;
    if (i >= plane) return;
    float m = mean[pc], iv = inv[pc];
    size_t idx = (size_t)pc * plane + i;
    x[idx] = fmaxf(0.f, (x[idx] - m) * iv);
}

// ---------------- segment mean (accum fused with L7 finalize) ---------------
__global__ void seg_zero(float* __restrict__ bins) {
    if (threadIdx.x < 128) bins[threadIdx.x] = 0.f;
}

// reads the 4 ic-split partials + bias, computes tanh inline; a7 never built.
__global__ void seg_accum_f(const float* __restrict__ part, const float* __restrict__ b,
                            const int* __restrict__ inst, float* __restrict__ bins,
                            int HW, size_t PS) {
    __shared__ float ls[128];  // 96 sums + 32 counts
    for (int i = threadIdx.x; i < 128; i += 256) ls[i] = 0.f;
    __syncthreads();
    int n = blockIdx.y;
    int i = blockIdx.x * 256 + threadIdx.x;
    if (i < HW) {
        int id = inst[(size_t)n * HW + i];
#pragma unroll
        for (int c = 0; c < 3; ++c) {
            size_t off = ((size_t)(n * 3 + c)) * HW + i;
            float v = part[off] + part[PS + off] + part[2 * PS + off] +
                      part[3 * PS + off] + b[c];
            atomicAdd(&ls[id * 3 + c], tanhf(v));
        }
        atomicAdd(&ls[96 + id], 1.0f);
    }
    __syncthreads();
    for (int i2 = threadIdx.x; i2 < 128; i2 += 256)
        if (ls[i2] != 0.f) atomicAdd(&bins[i2], ls[i2]);
}

__global__ void seg_scatter(const float* __restrict__ bins, const int* __restrict__ inst,
                            float* __restrict__ out, int HW) {
    int n = blockIdx.y;
    int i = blockIdx.x * 256 + threadIdx.x;
    if (i >= HW) return;
    int id = inst[(size_t)n * HW + i];
    float c = fmaxf(bins[96 + id], 1.0f);
    out[((size_t)n * 3 + 0) * HW + i] = bins[id * 3 + 0] / c;
    out[((size_t)n * 3 + 1) * HW + i] = bins[id * 3 + 1] / c;
    out[((size_t)n * 3 + 2) * HW + i] = bins[id * 3 + 2] / c;
}

// ---------------------------------------------------------------------------
extern "C" void kernel_launch(void* const* d_in, const int* in_sizes, int n_in,
                              void* d_out, int out_size, void* d_ws, size_t ws_size,
                              hipStream_t stream) {
    const float* x = (const float*)d_in[0];
    const int* inst = (const int*)d_in[1];
    const float* W[8];
    const float* B[8];
    for (int i = 0; i < 8; ++i) {
        W[i] = (const float*)d_in[2 + 2 * i];
        B[i] = (const float*)d_in[3 + 2 * i];
    }
    float* ws = (float*)d_ws;

    // End-aligned ping-pong arena (R2/R6 proven)
    const size_t S = 25165824;  // floats
    float* a0 = ws;                  // [8,32,256,256]
    float* a1 = ws + 16777216;       // [8,64,128,128]
    float* a2 = ws;                  // [8,128,64,64]
    float* a3 = ws + 23068672;       // [8,256,32,32]
    float* a4 = ws;                  // [8,128,63,63]
    float* a5 = ws + 17165824;       // [8,64,125,125]
    float* a6 = ws;                  // [8,32,249,249]  0 .. 15.87M
    float* PART = ws + 16000000;     // 4 x 1488024 floats (gap above a6)
    float* mean = ws + S;            // 2048
    float* inv = mean + 2048;        // 2048
    float* bins = inv + 2048;        // 128
    float* spart = bins + 128;       // 65536 (max nT*P = 256*256)
    float* sspart = spart + 65536;   // 65536

    // L0: 7x7 reflect, 3->32, 256. LDS-staged, OCPT=8, 8192 blocks
    conv7_lds<3, 8><<<dim3(256, 4, 8), 256, 0, stream>>>(
        x, W[0], B[0], a0, spart, sspart, 256, 32, 256, 256);
    stat_reduce_mi<<<dim3(256), 64, 0, stream>>>(spart, sspart, mean, inv, 256, 256, 1.f / 65536.f);
    inorm_apply4<<<dim3(IDIV(16384, 256), 256), 256, 0, stream>>>(a0, mean, inv, 16384);

    // L1: 3x3 s2, 32->64, 256->128. float4 rows, ICB=2, OCPT=8, 4096 blocks
    conv3s2_f4<32, 2, 8><<<dim3(64, 8, 8), 256, 0, stream>>>(
        a0, W[1], B[1], a1, spart, sspart, 512, 64, 256, 256, 128, 128);
    stat_reduce_mi<<<dim3(512), 64, 0, stream>>>(spart, sspart, mean, inv, 512, 64, 1.f / 16384.f);
    inorm_apply4<<<dim3(IDIV(4096, 256), 512), 256, 0, stream>>>(a1, mean, inv, 4096);

    // L2: 3x3 s2, 64->128, 128->64. float4 rows, 2048 blocks
    conv3s2_f4<64, 2, 8><<<dim3(16, 16, 8), 256, 0, stream>>>(
        a1, W[2], B[2], a2, spart, sspart, 1024, 128, 128, 128, 64, 64);
    stat_reduce_mi<<<dim3(1024), 64, 0, stream>>>(spart, sspart, mean, inv, 1024, 16, 1.f / 4096.f);
    inorm_apply4<<<dim3(IDIV(1024, 256), 1024), 256, 0, stream>>>(a2, mean, inv, 1024);

    // L3: 3x3 s2, 128->256, 64->32. float4 rows, 1024 blocks
    conv3s2_f4<128, 2, 8><<<dim3(4, 32, 8), 256, 0, stream>>>(
        a2, W[3], B[3], a3, spart, sspart, 2048, 256, 64, 64, 32, 32);
    stat_reduce_mi<<<dim3(2048), 64, 0, stream>>>(spart, sspart, mean, inv, 2048, 4, 1.f / 1024.f);
    inorm_apply4<<<dim3(1, 2048), 256, 0, stream>>>(a3, mean, inv, 256);

    // L4: convT, 256->128, 32->63. f2 inputs + 9xf4 weights, OCPT=4
    convt3_v4s<256, 4, 4><<<dim3(4, 32, 8), 256, 0, stream>>>(
        a3, W[4], B[4], a4, spart, sspart, 1024, 128, 32, 32, 63, 63);
    stat_reduce_mi<<<dim3(1024), 64, 0, stream>>>(spart, sspart, mean, inv, 1024, 4, 1.f / 3969.f);
    inorm_apply1<<<dim3(IDIV(3969, 256), 1024), 256, 0, stream>>>(a4, mean, inv, 3969);

    // L5: convT, 128->64, 63->125. OCPT=4, 2048 blocks
    convt3_v4s<128, 4, 4><<<dim3(16, 16, 8), 256, 0, stream>>>(
        a4, W[5], B[5], a5, spart, sspart, 512, 64, 63, 63, 125, 125);
    stat_reduce_mi<<<dim3(512), 64, 0, stream>>>(spart, sspart, mean, inv, 512, 16, 1.f / 15625.f);
    inorm_apply1<<<dim3(IDIV(15625, 256), 512), 256, 0, stream>>>(a5, mean, inv, 15625);

    // L6: convT, 64->32, 125->249. OCPT=4, 4096 blocks
    convt3_v4s<64, 4, 4><<<dim3(64, 8, 8), 256, 0, stream>>>(
        a5, W[6], B[6], a6, spart, sspart, 256, 32, 125, 125, 249, 249);
    stat_reduce_mi<<<dim3(256), 64, 0, stream>>>(spart, sspart, mean, inv, 256, 64, 1.f / 62001.f);
    inorm_apply1<<<dim3(IDIV(62001, 256), 256), 256, 0, stream>>>(a6, mean, inv, 62001);

    // L7: 7x7 reflect, 32->3, 249 — ic-split x4, LDS-staged
    conv7_part_lds<32, 8, 3><<<dim3(256, 4, 8), 256, 0, stream>>>(
        a6, W[7], PART, 1488024, 249, 249);

    // segment mean (accum reads partials + bias + tanh inline)
    seg_zero<<<1, 128, 0, stream>>>(bins);
    seg_accum_f<<<dim3(IDIV(62001, 256), 8), 256, 0, stream>>>(
        PART, B[7], inst, bins, 62001, 1488024);
    seg_scatter<<<dim3(IDIV(62001, 256), 8), 256, 0, stream>>>(bins, inst, (float*)d_out, 62001);
}

// Round 15
// 1215.710 us; speedup vs baseline: 1.2467x; 1.0318x over previous
//
#include <hip/hip_runtime.h>
#include <math.h>

// ---------------------------------------------------------------------------
// FeatureEncoder R33 = R32 (best, 1254us) + 2-pixel-per-thread convT on L5/L6.
// convT ledger: time invariant to occupancy (4-16 blk/CU), weight VMEM count,
// weight layout -> weights are on the SMEM pipe already; bottleneck is the
// per-wave serial chain (load -> wait -> 36 FMA per icl) with too little
// in-wave MLP. Fix: second output quad at qx+16 per thread: loads stay fully
// coalesced (unlike R21), weights SHARED between both pixels (unlike R20 -
// weight issue per output halves), 2 independent FMA/load chains per wave.
// L5: 1024 blocks (4/CU), L6: 2048 (8/CU) - still occupancy-safe; L4 kept at
// R32 single-pixel config as control (would drop to 2/CU).
// ICB=2 caps VGPR (~96). Stats nT updated (L5: 8 tiles, L6: 32).
// Everything else byte-identical to R32.
// ---------------------------------------------------------------------------

#define IDIV(a, b) (((a) + (b) - 1) / (b))

__device__ __forceinline__ int reflect_i(int i, int n) {
    i = i < 0 ? -i : i;
    return i >= n ? 2 * n - 2 - i : i;
}

__device__ __forceinline__ float ldb(const char* base, int boff) {
    return *(const float*)(base + boff);
}

// block-level (sum,sumsq) reduction for OCPT channels -> partial store
template <int OCPT>
__device__ __forceinline__ void stats_block_store(
    const float* sv, const float* ssv, float* __restrict__ spart,
    float* __restrict__ sspart, int P, int tile, int pc0) {
    __shared__ float redS[OCPT], redSS[OCPT];
    if (threadIdx.x < OCPT) { redS[threadIdx.x] = 0.f; redSS[threadIdx.x] = 0.f; }
    __syncthreads();
    int lane = threadIdx.x & 63;
#pragma unroll
    for (int j = 0; j < OCPT; ++j) {
        float s = sv[j], ss = ssv[j];
#pragma unroll
        for (int o = 32; o > 0; o >>= 1) {
            s += __shfl_down(s, o);
            ss += __shfl_down(ss, o);
        }
        if (lane == 0) { atomicAdd(&redS[j], s); atomicAdd(&redSS[j], ss); }  // LDS atomics
    }
    __syncthreads();
    if (threadIdx.x < OCPT) {
        spart[(size_t)tile * P + pc0 + threadIdx.x] = redS[threadIdx.x];
        sspart[(size_t)tile * P + pc0 + threadIdx.x] = redSS[threadIdx.x];
    }
}

// fold [nT][P] partials -> mean, inv (one wavefront per plane)
__global__ __launch_bounds__(64) void stat_reduce_mi(
    const float* __restrict__ sp, const float* __restrict__ ssp,
    float* __restrict__ mean, float* __restrict__ inv, int P, int nT,
    float rcp_plane) {
    int p = blockIdx.x;
    float a = 0.f, bsum = 0.f;
    for (int t = threadIdx.x; t < nT; t += 64) {
        a += sp[(size_t)t * P + p];
        bsum += ssp[(size_t)t * P + p];
    }
#pragma unroll
    for (int o = 32; o > 0; o >>= 1) {
        a += __shfl_down(a, o);
        bsum += __shfl_down(bsum, o);
    }
    if (threadIdx.x == 0) {
        float m = a * rcp_plane;
        float var = bsum * rcp_plane - m * m;
        mean[p] = m;
        inv[p] = rsqrtf(var + 1e-5f);
    }
}

// ---------------- 7x7 same-conv (L0), LDS-staged tile, fused stats ----------
template <int CIN, int OCPT>
__global__ __launch_bounds__(256) void conv7_lds(
    const float* __restrict__ x, const float* __restrict__ w,
    const float* __restrict__ b, float* __restrict__ y,
    float* __restrict__ spart, float* __restrict__ sspart, int P,
    int Cout, int H, int W) {
    constexpr int TR = 22, TC = 22, RS = 24;
    __shared__ float s[CIN][TR][RS];
    int tx = threadIdx.x & 15, ty = threadIdx.x >> 4;
    int tilesX = W / 16;
    int bx = blockIdx.x % tilesX, by = blockIdx.x / tilesX;
    int oh0 = by * 16, ow0 = bx * 16;
    int oc0 = blockIdx.y * OCPT;
    int n = blockIdx.z;
    const float* xn = x + (size_t)n * CIN * H * W;

    for (int q = threadIdx.x; q < CIN * TR * TC; q += 256) {
        int p = q / (TR * TC), rem = q % (TR * TC);
        int r = rem / TC, c = rem % TC;
        int ih = reflect_i(oh0 + r - 3, H);
        int iw = reflect_i(ow0 + c - 3, W);
        s[p][r][c] = xn[(size_t)p * H * W + (size_t)ih * W + iw];
    }
    __syncthreads();

    float acc[OCPT];
#pragma unroll
    for (int j = 0; j < OCPT; ++j) acc[j] = 0.f;

    for (int ic = 0; ic < CIN; ++ic) {
        const float* wp = w + ((size_t)oc0 * CIN + ic) * 49;
#pragma unroll
        for (int kh = 0; kh < 7; ++kh) {
#pragma unroll
            for (int kw = 0; kw < 7; ++kw) {
                float vt = s[ic][ty + kh][tx + kw];
#pragma unroll
                for (int j = 0; j < OCPT; ++j)
                    acc[j] += vt * wp[(size_t)j * CIN * 49 + kh * 7 + kw];
            }
        }
    }

    int oh = oh0 + ty, ow = ow0 + tx;
    float sv[OCPT], ssv[OCPT];
#pragma unroll
    for (int j = 0; j < OCPT; ++j) {
        float r = acc[j] + b[oc0 + j];
        y[(((size_t)n * Cout + oc0 + j) * H + oh) * W + ow] = r;
        sv[j] = r;
        ssv[j] = r * r;
    }
    stats_block_store<OCPT>(sv, ssv, spart, sspart, P, blockIdx.x, n * Cout + oc0);
}

// ---------------- 7x7 conv, ic-split partial (L7), LDS-staged ---------------
template <int CINTOT, int ICPB, int OCPT>
__global__ __launch_bounds__(256) void conv7_part_lds(
    const float* __restrict__ x, const float* __restrict__ w,
    float* __restrict__ part, size_t PS, int H, int W) {
    constexpr int TR = 22, TC = 22, RS = 24;
    __shared__ float s[ICPB][TR][RS];
    int tx = threadIdx.x & 15, ty = threadIdx.x >> 4;
    int tilesX = IDIV(W, 16);
    int bx = blockIdx.x % tilesX, by = blockIdx.x / tilesX;
    int oh0 = by * 16, ow0 = bx * 16;
    int ks = blockIdx.y;
    int n = blockIdx.z;
    const int ic0 = ks * ICPB;
    const float* xn = x + (size_t)n * CINTOT * H * W;

    for (int q = threadIdx.x; q < ICPB * TR * TC; q += 256) {
        int p = q / (TR * TC), rem = q % (TR * TC);
        int r = rem / TC, c = rem % TC;
        int ih = reflect_i(oh0 + r - 3, H);
        int iw = reflect_i(ow0 + c - 3, W);
        s[p][r][c] = xn[(size_t)(ic0 + p) * H * W + (size_t)ih * W + iw];
    }
    __syncthreads();

    float acc[OCPT];
#pragma unroll
    for (int j = 0; j < OCPT; ++j) acc[j] = 0.f;

#pragma unroll
    for (int icl = 0; icl < ICPB; ++icl) {
        const float* wp = w + (size_t)(ic0 + icl) * 49;
#pragma unroll
        for (int kh = 0; kh < 7; ++kh) {
#pragma unroll
            for (int kw = 0; kw < 7; ++kw) {
                float vt = s[icl][ty + kh][tx + kw];
#pragma unroll
                for (int j = 0; j < OCPT; ++j)
                    acc[j] += vt * wp[(size_t)j * CINTOT * 49 + kh * 7 + kw];
            }
        }
    }

    int oh = oh0 + ty, ow = ow0 + tx;
    if (oh < H && ow < W) {
#pragma unroll
        for (int j = 0; j < OCPT; ++j)
            part[(size_t)ks * PS + (((size_t)n * OCPT + j) * H + oh) * W + ow] = acc[j];
    }
}

// ---------------- 3x3 s2 conv, float4 rows + f4 weights, fused stats --------
template <int CIN, int ICB, int OCPT>
__global__ __launch_bounds__(256) void conv3s2_f4(
    const float* __restrict__ x, const float* __restrict__ w,
    const float* __restrict__ b, float* __restrict__ y,
    float* __restrict__ spart, float* __restrict__ sspart, int P,
    int Cout, int Hin, int Win, int Hout, int Wout) {
    int tx = threadIdx.x & 15, ty = threadIdx.x >> 4;
    int tilesX = Wout >> 4;
    int ow = (blockIdx.x % tilesX) * 16 + tx;
    int oh = (blockIdx.x / tilesX) * 16 + ty;
    int oc0 = blockIdx.y * OCPT;
    int n = blockIdx.z;

    int iw0 = ow * 2 - 1;
    bool shb = iw0 < 0;                 // only ow==0 lanes
    int cb = shb ? 0 : iw0;             // clamped base col, in [0, Win-3]
    int ih0 = oh * 2 - 1;
    int rof[3];
    float mr[3];
#pragma unroll
    for (int kh = 0; kh < 3; ++kh) {
        int ih = ih0 + kh;
        int ihc = min(max(ih, 0), Hin - 1);
        rof[kh] = (ihc * Win + cb) * 4;
        mr[kh] = (ih >= 0 && ih < Hin) ? 1.f : 0.f;
    }

    float acc[OCPT];
#pragma unroll
    for (int j = 0; j < OCPT; ++j) acc[j] = 0.f;

    const char* xb = (const char*)x + (size_t)n * CIN * Hin * Win * 4;
    const int HWb = Hin * Win * 4;

    for (int ic0 = 0; ic0 < CIN; ic0 += ICB) {
        float t[ICB][9];
#pragma unroll
        for (int icl = 0; icl < ICB; ++icl) {
            const char* xp = xb + (size_t)(ic0 + icl) * HWb;  // uniform advance
#pragma unroll
            for (int kh = 0; kh < 3; ++kh) {
                float4 v = *(const float4*)(xp + rof[kh]);
                float e0 = shb ? 0.f : v.x;
                float e1 = shb ? v.x : v.y;
                float e2 = shb ? v.y : v.z;
                t[icl][kh * 3 + 0] = e0 * mr[kh];
                t[icl][kh * 3 + 1] = e1 * mr[kh];
                t[icl][kh * 3 + 2] = e2 * mr[kh];
            }
        }
#pragma unroll
        for (int icl = 0; icl < ICB; ++icl) {
            const float* wp = w + ((size_t)oc0 * CIN + ic0 + icl) * 9;
#pragma unroll
            for (int j = 0; j < OCPT; ++j) {
                const float* wj = wp + (size_t)j * CIN * 9;
                float4 wa = *(const float4*)wj;
                float4 wb = *(const float4*)(wj + 4);
                float w8 = wj[8];
                acc[j] += t[icl][0] * wa.x + t[icl][1] * wa.y + t[icl][2] * wa.z +
                          t[icl][3] * wa.w + t[icl][4] * wb.x + t[icl][5] * wb.y +
                          t[icl][6] * wb.z + t[icl][7] * wb.w + t[icl][8] * w8;
            }
        }
    }
    float sv[OCPT], ssv[OCPT];
#pragma unroll
    for (int j = 0; j < OCPT; ++j) {
        float r = acc[j] + b[oc0 + j];
        y[(((size_t)n * Cout + oc0 + j) * Hout + oh) * Wout + ow] = r;
        sv[j] = r;
        ssv[j] = r * r;
    }
    stats_block_store<OCPT>(sv, ssv, spart, sspart, P, blockIdx.x, n * Cout + oc0);
}

// ---------------- 3x3 s2 transposed conv, quad, f2 inputs, 9xf4 weights -----
// Single-pixel version (L4 control). torch weight layout w[Cin][Cout][3][3].
template <int CIN, int ICB, int OCPT>
__global__ __launch_bounds__(256) void convt3_v4s(
    const float* __restrict__ x, const float* __restrict__ w,
    const float* __restrict__ b, float* __restrict__ y,
    float* __restrict__ spart, float* __restrict__ sspart, int P,
    int Cout, int Hin, int Win, int Hout, int Wout) {
    static_assert(OCPT == 4, "9xf4 weight path assumes OCPT==4");
    int tx = threadIdx.x & 15, ty = threadIdx.x >> 4;
    int tilesX = IDIV(Win, 16);
    int qx = (blockIdx.x % tilesX) * 16 + tx;
    int qy = (blockIdx.x / tilesX) * 16 + ty;
    int oc0 = blockIdx.y * OCPT;
    int n = blockIdx.z;
    bool valid = (qx < Win) && (qy < Hin);
    int qxc = min(qx, Win - 1), qyc = min(qy, Hin - 1);
    bool xin = valid && (qx + 1 < Win), yin = valid && (qy + 1 < Hin);
    int o10 = yin ? Win : 0;
    float m01 = xin ? 1.f : 0.f, m10 = yin ? 1.f : 0.f, m11 = m01 * m10;

    int p00 = (qyc * Win + qxc) * 4;
    int p10 = p00 + o10 * 4;

    float a00[OCPT], a01[OCPT], a10[OCPT], a11[OCPT];
#pragma unroll
    for (int j = 0; j < OCPT; ++j) { a00[j] = a01[j] = a10[j] = a11[j] = 0.f; }

    const char* xb = (const char*)x + (size_t)n * CIN * Hin * Win * 4;  // uniform
    const int HWb = Hin * Win * 4;

    float va[ICB][4], vb[ICB][4];
    auto load = [&](float (&v)[ICB][4], int ic0) {
#pragma unroll
        for (int icl = 0; icl < ICB; ++icl) {
            const char* xp = xb + (size_t)(ic0 + icl) * HWb;  // uniform advance
            float2 u = *(const float2*)(xp + p00);
            float2 d = *(const float2*)(xp + p10);
            v[icl][0] = u.x;
            v[icl][1] = u.y * m01;
            v[icl][2] = d.x * m10;
            v[icl][3] = d.y * m11;
        }
    };
    auto fma = [&](const float (&v)[ICB][4], int ic0) {
#pragma unroll
        for (int icl = 0; icl < ICB; ++icl) {
            const float* wp = w + ((size_t)(ic0 + icl) * Cout + oc0) * 9;
            float4 q[9];
#pragma unroll
            for (int c = 0; c < 9; ++c) q[c] = *(const float4*)(wp + 4 * c);
            const float* wf = (const float*)q;   // 36 floats, const-indexed
#pragma unroll
            for (int j = 0; j < OCPT; ++j) {
                float w0 = wf[j * 9 + 0], w1 = wf[j * 9 + 1], w2 = wf[j * 9 + 2];
                float w3 = wf[j * 9 + 3], w4 = wf[j * 9 + 4], w5 = wf[j * 9 + 5];
                float w6 = wf[j * 9 + 6], w7 = wf[j * 9 + 7], w8 = wf[j * 9 + 8];
                a00[j] += w4 * v[icl][0];
                a01[j] += w5 * v[icl][0] + w3 * v[icl][1];
                a10[j] += w7 * v[icl][0] + w1 * v[icl][2];
                a11[j] += w8 * v[icl][0] + w6 * v[icl][1] + w2 * v[icl][2] +
                          w0 * v[icl][3];
            }
        }
    };

    load(va, 0);
    for (int ic0 = 0; ic0 < CIN; ic0 += 2 * ICB) {
        load(vb, ic0 + ICB);
        fma(va, ic0);
        load(va, min(ic0 + 2 * ICB, CIN - ICB));
        fma(vb, ic0 + ICB);
    }

    int oh = 2 * qy, ow = 2 * qx;
    float sv[OCPT], ssv[OCPT];
#pragma unroll
    for (int j = 0; j < OCPT; ++j) {
        float s = 0.f, ss = 0.f;
        if (valid) {
            float bb = b[oc0 + j];
            float* yp = y + (((size_t)n * Cout + oc0 + j) * Hout + oh) * Wout + ow;
            float t00 = a00[j] + bb;
            yp[0] = t00; s += t00; ss += t00 * t00;
            if (xin) { float t = a01[j] + bb; yp[1] = t; s += t; ss += t * t; }
            if (yin) { float t = a10[j] + bb; yp[Wout] = t; s += t; ss += t * t; }
            if (xin && yin) { float t = a11[j] + bb; yp[Wout + 1] = t; s += t; ss += t * t; }
        }
        sv[j] = s; ssv[j] = ss;
    }
    stats_block_store<OCPT>(sv, ssv, spart, sspart, P, blockIdx.x, n * Cout + oc0);
}

// ---------------- convT, 2 pixels/thread (qx, qx+16), shared weights --------
// Block covers 32 cols x 16 rows of input quads. Weights loaded once per
// (icl,j), used by BOTH pixels -> weight issue per output halves; 2
// independent load/FMA chains per wave for latency hiding. ICB=2 (VGPR cap).
template <int CIN, int ICB, int OCPT>
__global__ __launch_bounds__(256) void convt3_x2(
    const float* __restrict__ x, const float* __restrict__ w,
    const float* __restrict__ b, float* __restrict__ y,
    float* __restrict__ spart, float* __restrict__ sspart, int P,
    int Cout, int Hin, int Win, int Hout, int Wout) {
    int tx = threadIdx.x & 15, ty = threadIdx.x >> 4;
    int tilesX = IDIV(Win, 32);
    int bx = blockIdx.x % tilesX, by = blockIdx.x / tilesX;
    int qy = by * 16 + ty;
    int oc0 = blockIdx.y * OCPT;
    int n = blockIdx.z;

    int qxs[2];
    qxs[0] = bx * 32 + tx;
    qxs[1] = qxs[0] + 16;
    bool vldp[2], xinp[2], yinp[2];
    int p00[2], p10[2];
    float m01[2], m10[2], m11[2];
#pragma unroll
    for (int p = 0; p < 2; ++p) {
        bool valid = (qxs[p] < Win) && (qy < Hin);
        int qxc = min(qxs[p], Win - 1), qyc = min(qy, Hin - 1);
        bool xin = valid && (qxs[p] + 1 < Win);
        bool yin = valid && (qy + 1 < Hin);
        vldp[p] = valid; xinp[p] = xin; yinp[p] = yin;
        int o10 = yin ? Win : 0;
        m01[p] = xin ? 1.f : 0.f;
        m10[p] = yin ? 1.f : 0.f;
        m11[p] = m01[p] * m10[p];
        p00[p] = (qyc * Win + qxc) * 4;
        p10[p] = p00[p] + o10 * 4;
    }

    float a00[2][OCPT], a01[2][OCPT], a10[2][OCPT], a11[2][OCPT];
#pragma unroll
    for (int p = 0; p < 2; ++p)
#pragma unroll
        for (int j = 0; j < OCPT; ++j) {
            a00[p][j] = a01[p][j] = a10[p][j] = a11[p][j] = 0.f;
        }

    const char* xb = (const char*)x + (size_t)n * CIN * Hin * Win * 4;  // uniform
    const int HWb = Hin * Win * 4;

    float va[ICB][2][4], vb[ICB][2][4];
    auto load = [&](float (&v)[ICB][2][4], int ic0) {
#pragma unroll
        for (int icl = 0; icl < ICB; ++icl) {
            const char* xp = xb + (size_t)(ic0 + icl) * HWb;  // uniform advance
#pragma unroll
            for (int p = 0; p < 2; ++p) {
                float2 u = *(const float2*)(xp + p00[p]);
                float2 d = *(const float2*)(xp + p10[p]);
                v[icl][p][0] = u.x;
                v[icl][p][1] = u.y * m01[p];
                v[icl][p][2] = d.x * m10[p];
                v[icl][p][3] = d.y * m11[p];
            }
        }
    };
    auto fma = [&](const float (&v)[ICB][2][4], int ic0) {
#pragma unroll
        for (int icl = 0; icl < ICB; ++icl) {
            const float* wp = w + ((size_t)(ic0 + icl) * Cout + oc0) * 9;
#pragma unroll
            for (int j = 0; j < OCPT; ++j) {
                const float* wj = wp + j * 9;
                float4 wa = *(const float4*)wj;        // w0 w1 w2 w3
                float4 wb = *(const float4*)(wj + 4);  // w4 w5 w6 w7
                float w8 = wj[8];
#pragma unroll
                for (int p = 0; p < 2; ++p) {
                    a00[p][j] += wb.x * v[icl][p][0];
                    a01[p][j] += wb.y * v[icl][p][0] + wa.w * v[icl][p][1];
                    a10[p][j] += wb.w * v[icl][p][0] + wa.y * v[icl][p][2];
                    a11[p][j] += w8 * v[icl][p][0] + wb.z * v[icl][p][1] +
                                 wa.z * v[icl][p][2] + wa.x * v[icl][p][3];
                }
            }
        }
    };

    load(va, 0);
    for (int ic0 = 0; ic0 < CIN; ic0 += 2 * ICB) {
        load(vb, ic0 + ICB);
        fma(va, ic0);
        load(va, min(ic0 + 2 * ICB, CIN - ICB));
        fma(vb, ic0 + ICB);
    }

    int oh = 2 * qy;
    float sv[OCPT], ssv[OCPT];
#pragma unroll
    for (int j = 0; j < OCPT; ++j) {
        float s = 0.f, ss = 0.f;
        float bb = b[oc0 + j];
#pragma unroll
        for (int p = 0; p < 2; ++p) {
            if (vldp[p]) {
                int ow = 2 * qxs[p];
                float* yp = y + (((size_t)n * Cout + oc0 + j) * Hout + oh) * Wout + ow;
                float t00 = a00[p][j] + bb;
                yp[0] = t00; s += t00; ss += t00 * t00;
                if (xinp[p]) { float t = a01[p][j] + bb; yp[1] = t; s += t; ss += t * t; }
                if (yinp[p]) { float t = a10[p][j] + bb; yp[Wout] = t; s += t; ss += t * t; }
                if (xinp[p] && yinp[p]) {
                    float t = a11[p][j] + bb;
                    yp[Wout + 1] = t; s += t; ss += t * t;
                }
            }
        }
        sv[j] = s; ssv[j] = ss;
    }
    stats_block_store<OCPT>(sv, ssv, spart, sspart, P, blockIdx.x, n * Cout + oc0);
}

// ---------------- inorm apply, float4 coalesced (plane % 4 == 0) ------------
__global__ void inorm_apply4(float* __restrict__ x, const float* __restrict__ mean,
                             const float* __restrict__ inv, int plane4) {
    int pc = blockIdx.y;
    int i = blockIdx.x * 256 + threadIdx.x;
    if (i >= plane4) return;
    float m = mean[pc], iv = inv[pc];
    float4* p = (float4*)(x + (size_t)pc * plane4 * 4);
    float4 v = p[i];
    v.x = fmaxf(0.f, (v.x - m) * iv);
    v.y = fmaxf(0.f, (v.y - m) * iv);
    v.z = fmaxf(0.f, (v.z - m) * iv);
    v.w = fmaxf(0.f, (v.w - m) * iv);
    p[i] = v;
}

// ---------------- inorm apply, 1 elem/thread coalesced (any plane) ----------
__global__ void inorm_apply1(float* __restrict__ x, const float* __restrict__ mean,
                             const float* __restrict__ inv, int plane) {
    int pc = blockIdx.y;
    int i = blockIdx.x * 256 + threadIdx.x;
    if (i >= plane) return;
    float m = mean[pc], iv = inv[pc];
    size_t idx = (size_t)pc * plane + i;
    x[idx] = fmaxf(0.f, (x[idx] - m) * iv);
}

// ---------------- segment mean (accum fused with L7 finalize) ---------------
__global__ void seg_zero(float* __restrict__ bins) {
    if (threadIdx.x < 128) bins[threadIdx.x] = 0.f;
}

// reads the 4 ic-split partials + bias, computes tanh inline; a7 never built.
__global__ void seg_accum_f(const float* __restrict__ part, const float* __restrict__ b,
                            const int* __restrict__ inst, float* __restrict__ bins,
                            int HW, size_t PS) {
    __shared__ float ls[128];  // 96 sums + 32 counts
    for (int i = threadIdx.x; i < 128; i += 256) ls[i] = 0.f;
    __syncthreads();
    int n = blockIdx.y;
    int i = blockIdx.x * 256 + threadIdx.x;
    if (i < HW) {
        int id = inst[(size_t)n * HW + i];
#pragma unroll
        for (int c = 0; c < 3; ++c) {
            size_t off = ((size_t)(n * 3 + c)) * HW + i;
            float v = part[off] + part[PS + off] + part[2 * PS + off] +
                      part[3 * PS + off] + b[c];
            atomicAdd(&ls[id * 3 + c], tanhf(v));
        }
        atomicAdd(&ls[96 + id], 1.0f);
    }
    __syncthreads();
    for (int i2 = threadIdx.x; i2 < 128; i2 += 256)
        if (ls[i2] != 0.f) atomicAdd(&bins[i2], ls[i2]);
}

__global__ void seg_scatter(const float* __restrict__ bins, const int* __restrict__ inst,
                            float* __restrict__ out, int HW) {
    int n = blockIdx.y;
    int i = blockIdx.x * 256 + threadIdx.x;
    if (i >= HW) return;
    int id = inst[(size_t)n * HW + i];
    float c = fmaxf(bins[96 + id], 1.0f);
    out[((size_t)n * 3 + 0) * HW + i] = bins[id * 3 + 0] / c;
    out[((size_t)n * 3 + 1) * HW + i] = bins[id * 3 + 1] / c;
    out[((size_t)n * 3 + 2) * HW + i] = bins[id * 3 + 2] / c;
}

// ---------------------------------------------------------------------------
extern "C" void kernel_launch(void* const* d_in, const int* in_sizes, int n_in,
                              void* d_out, int out_size, void* d_ws, size_t ws_size,
                              hipStream_t stream) {
    const float* x = (const float*)d_in[0];
    const int* inst = (const int*)d_in[1];
    const float* W[8];
    const float* B[8];
    for (int i = 0; i < 8; ++i) {
        W[i] = (const float*)d_in[2 + 2 * i];
        B[i] = (const float*)d_in[3 + 2 * i];
    }
    float* ws = (float*)d_ws;

    // End-aligned ping-pong arena (R2/R6 proven)
    const size_t S = 25165824;  // floats
    float* a0 = ws;                  // [8,32,256,256]
    float* a1 = ws + 16777216;       // [8,64,128,128]
    float* a2 = ws;                  // [8,128,64,64]
    float* a3 = ws + 23068672;       // [8,256,32,32]
    float* a4 = ws;                  // [8,128,63,63]
    float* a5 = ws + 17165824;       // [8,64,125,125]
    float* a6 = ws;                  // [8,32,249,249]  0 .. 15.87M
    float* PART = ws + 16000000;     // 4 x 1488024 floats (gap above a6)
    float* mean = ws + S;            // 2048
    float* inv = mean + 2048;        // 2048
    float* bins = inv + 2048;        // 128
    float* spart = bins + 128;       // 65536 (max nT*P = 256*256)
    float* sspart = spart + 65536;   // 65536

    // L0: 7x7 reflect, 3->32, 256. LDS-staged, OCPT=8, 8192 blocks
    conv7_lds<3, 8><<<dim3(256, 4, 8), 256, 0, stream>>>(
        x, W[0], B[0], a0, spart, sspart, 256, 32, 256, 256);
    stat_reduce_mi<<<dim3(256), 64, 0, stream>>>(spart, sspart, mean, inv, 256, 256, 1.f / 65536.f);
    inorm_apply4<<<dim3(IDIV(16384, 256), 256), 256, 0, stream>>>(a0, mean, inv, 16384);

    // L1: 3x3 s2, 32->64, 256->128. float4 rows, ICB=2, OCPT=8, 4096 blocks
    conv3s2_f4<32, 2, 8><<<dim3(64, 8, 8), 256, 0, stream>>>(
        a0, W[1], B[1], a1, spart, sspart, 512, 64, 256, 256, 128, 128);
    stat_reduce_mi<<<dim3(512), 64, 0, stream>>>(spart, sspart, mean, inv, 512, 64, 1.f / 16384.f);
    inorm_apply4<<<dim3(IDIV(4096, 256), 512), 256, 0, stream>>>(a1, mean, inv, 4096);

    // L2: 3x3 s2, 64->128, 128->64. float4 rows, 2048 blocks
    conv3s2_f4<64, 2, 8><<<dim3(16, 16, 8), 256, 0, stream>>>(
        a1, W[2], B[2], a2, spart, sspart, 1024, 128, 128, 128, 64, 64);
    stat_reduce_mi<<<dim3(1024), 64, 0, stream>>>(spart, sspart, mean, inv, 1024, 16, 1.f / 4096.f);
    inorm_apply4<<<dim3(IDIV(1024, 256), 1024), 256, 0, stream>>>(a2, mean, inv, 1024);

    // L3: 3x3 s2, 128->256, 64->32. float4 rows, 1024 blocks
    conv3s2_f4<128, 2, 8><<<dim3(4, 32, 8), 256, 0, stream>>>(
        a2, W[3], B[3], a3, spart, sspart, 2048, 256, 64, 64, 32, 32);
    stat_reduce_mi<<<dim3(2048), 64, 0, stream>>>(spart, sspart, mean, inv, 2048, 4, 1.f / 1024.f);
    inorm_apply4<<<dim3(1, 2048), 256, 0, stream>>>(a3, mean, inv, 256);

    // L4: convT, 256->128, 32->63. Single-pixel control (R32 config)
    convt3_v4s<256, 4, 4><<<dim3(4, 32, 8), 256, 0, stream>>>(
        a3, W[4], B[4], a4, spart, sspart, 1024, 128, 32, 32, 63, 63);
    stat_reduce_mi<<<dim3(1024), 64, 0, stream>>>(spart, sspart, mean, inv, 1024, 4, 1.f / 3969.f);
    inorm_apply1<<<dim3(IDIV(3969, 256), 1024), 256, 0, stream>>>(a4, mean, inv, 3969);

    // L5: convT, 128->64, 63->125. 2px/thread, 1024 blocks (8 tiles)
    convt3_x2<128, 2, 4><<<dim3(8, 16, 8), 256, 0, stream>>>(
        a4, W[5], B[5], a5, spart, sspart, 512, 64, 63, 63, 125, 125);
    stat_reduce_mi<<<dim3(512), 64, 0, stream>>>(spart, sspart, mean, inv, 512, 8, 1.f / 15625.f);
    inorm_apply1<<<dim3(IDIV(15625, 256), 512), 256, 0, stream>>>(a5, mean, inv, 15625);

    // L6: convT, 64->32, 125->249. 2px/thread, 2048 blocks (32 tiles)
    convt3_x2<64, 2, 4><<<dim3(32, 8, 8), 256, 0, stream>>>(
        a5, W[6], B[6], a6, spart, sspart, 256, 32, 125, 125, 249, 249);
    stat_reduce_mi<<<dim3(256), 64, 0, stream>>>(spart, sspart, mean, inv, 256, 32, 1.f / 62001.f);
    inorm_apply1<<<dim3(IDIV(62001, 256), 256), 256, 0, stream>>>(a6, mean, inv, 62001);

    // L7: 7x7 reflect, 32->3, 249 — ic-split x4, LDS-staged
    conv7_part_lds<32, 8, 3><<<dim3(256, 4, 8), 256, 0, stream>>>(
        a6, W[7], PART, 1488024, 249, 249);

    // segment mean (accum reads partials + bias + tanh inline)
    seg_zero<<<1, 128, 0, stream>>>(bins);
    seg_accum_f<<<dim3(IDIV(62001, 256), 8), 256, 0, stream>>>(
        PART, B[7], inst, bins, 62001, 1488024);
    seg_scatter<<<dim3(IDIV(62001, 256), 8), 256, 0, stream>>>(bins, inst, (float*)d_out, 62001);
}

// Round 16
// 1167.486 us; speedup vs baseline: 1.2982x; 1.0413x over previous
//
#include <hip/hip_runtime.h>
#include <math.h>

// ---------------------------------------------------------------------------
// FeatureEncoder R34 = R33 (best, 1216us) + 2px/thread convT extended to L4.
// R33 confirmed the mechanism: convT stall = per-wave serial load->FMA chain;
// 2 weight-sharing pixels/thread = 2 independent chains, zero coalescing or
// weight-traffic cost -> L5/L6 dropped out of top-5 (~40us saved). L4 (the
// R33 control) now owns the top-5 at 158-161us. Extend: L4 -> convt3_x2
// <256,2,4>, grid (2,32,8)=512 blocks (2/CU - acceptable: convT time proven
// occupancy-invariant 4..16 blk/CU; chains, not waves, are the lever).
// stat_reduce L4 nT: 4 -> 2. Everything else byte-identical to R33.
// ---------------------------------------------------------------------------

#define IDIV(a, b) (((a) + (b) - 1) / (b))

__device__ __forceinline__ int reflect_i(int i, int n) {
    i = i < 0 ? -i : i;
    return i >= n ? 2 * n - 2 - i : i;
}

__device__ __forceinline__ float ldb(const char* base, int boff) {
    return *(const float*)(base + boff);
}

// block-level (sum,sumsq) reduction for OCPT channels -> partial store
template <int OCPT>
__device__ __forceinline__ void stats_block_store(
    const float* sv, const float* ssv, float* __restrict__ spart,
    float* __restrict__ sspart, int P, int tile, int pc0) {
    __shared__ float redS[OCPT], redSS[OCPT];
    if (threadIdx.x < OCPT) { redS[threadIdx.x] = 0.f; redSS[threadIdx.x] = 0.f; }
    __syncthreads();
    int lane = threadIdx.x & 63;
#pragma unroll
    for (int j = 0; j < OCPT; ++j) {
        float s = sv[j], ss = ssv[j];
#pragma unroll
        for (int o = 32; o > 0; o >>= 1) {
            s += __shfl_down(s, o);
            ss += __shfl_down(ss, o);
        }
        if (lane == 0) { atomicAdd(&redS[j], s); atomicAdd(&redSS[j], ss); }  // LDS atomics
    }
    __syncthreads();
    if (threadIdx.x < OCPT) {
        spart[(size_t)tile * P + pc0 + threadIdx.x] = redS[threadIdx.x];
        sspart[(size_t)tile * P + pc0 + threadIdx.x] = redSS[threadIdx.x];
    }
}

// fold [nT][P] partials -> mean, inv (one wavefront per plane)
__global__ __launch_bounds__(64) void stat_reduce_mi(
    const float* __restrict__ sp, const float* __restrict__ ssp,
    float* __restrict__ mean, float* __restrict__ inv, int P, int nT,
    float rcp_plane) {
    int p = blockIdx.x;
    float a = 0.f, bsum = 0.f;
    for (int t = threadIdx.x; t < nT; t += 64) {
        a += sp[(size_t)t * P + p];
        bsum += ssp[(size_t)t * P + p];
    }
#pragma unroll
    for (int o = 32; o > 0; o >>= 1) {
        a += __shfl_down(a, o);
        bsum += __shfl_down(bsum, o);
    }
    if (threadIdx.x == 0) {
        float m = a * rcp_plane;
        float var = bsum * rcp_plane - m * m;
        mean[p] = m;
        inv[p] = rsqrtf(var + 1e-5f);
    }
}

// ---------------- 7x7 same-conv (L0), LDS-staged tile, fused stats ----------
template <int CIN, int OCPT>
__global__ __launch_bounds__(256) void conv7_lds(
    const float* __restrict__ x, const float* __restrict__ w,
    const float* __restrict__ b, float* __restrict__ y,
    float* __restrict__ spart, float* __restrict__ sspart, int P,
    int Cout, int H, int W) {
    constexpr int TR = 22, TC = 22, RS = 24;
    __shared__ float s[CIN][TR][RS];
    int tx = threadIdx.x & 15, ty = threadIdx.x >> 4;
    int tilesX = W / 16;
    int bx = blockIdx.x % tilesX, by = blockIdx.x / tilesX;
    int oh0 = by * 16, ow0 = bx * 16;
    int oc0 = blockIdx.y * OCPT;
    int n = blockIdx.z;
    const float* xn = x + (size_t)n * CIN * H * W;

    for (int q = threadIdx.x; q < CIN * TR * TC; q += 256) {
        int p = q / (TR * TC), rem = q % (TR * TC);
        int r = rem / TC, c = rem % TC;
        int ih = reflect_i(oh0 + r - 3, H);
        int iw = reflect_i(ow0 + c - 3, W);
        s[p][r][c] = xn[(size_t)p * H * W + (size_t)ih * W + iw];
    }
    __syncthreads();

    float acc[OCPT];
#pragma unroll
    for (int j = 0; j < OCPT; ++j) acc[j] = 0.f;

    for (int ic = 0; ic < CIN; ++ic) {
        const float* wp = w + ((size_t)oc0 * CIN + ic) * 49;
#pragma unroll
        for (int kh = 0; kh < 7; ++kh) {
#pragma unroll
            for (int kw = 0; kw < 7; ++kw) {
                float vt = s[ic][ty + kh][tx + kw];
#pragma unroll
                for (int j = 0; j < OCPT; ++j)
                    acc[j] += vt * wp[(size_t)j * CIN * 49 + kh * 7 + kw];
            }
        }
    }

    int oh = oh0 + ty, ow = ow0 + tx;
    float sv[OCPT], ssv[OCPT];
#pragma unroll
    for (int j = 0; j < OCPT; ++j) {
        float r = acc[j] + b[oc0 + j];
        y[(((size_t)n * Cout + oc0 + j) * H + oh) * W + ow] = r;
        sv[j] = r;
        ssv[j] = r * r;
    }
    stats_block_store<OCPT>(sv, ssv, spart, sspart, P, blockIdx.x, n * Cout + oc0);
}

// ---------------- 7x7 conv, ic-split partial (L7), LDS-staged ---------------
template <int CINTOT, int ICPB, int OCPT>
__global__ __launch_bounds__(256) void conv7_part_lds(
    const float* __restrict__ x, const float* __restrict__ w,
    float* __restrict__ part, size_t PS, int H, int W) {
    constexpr int TR = 22, TC = 22, RS = 24;
    __shared__ float s[ICPB][TR][RS];
    int tx = threadIdx.x & 15, ty = threadIdx.x >> 4;
    int tilesX = IDIV(W, 16);
    int bx = blockIdx.x % tilesX, by = blockIdx.x / tilesX;
    int oh0 = by * 16, ow0 = bx * 16;
    int ks = blockIdx.y;
    int n = blockIdx.z;
    const int ic0 = ks * ICPB;
    const float* xn = x + (size_t)n * CINTOT * H * W;

    for (int q = threadIdx.x; q < ICPB * TR * TC; q += 256) {
        int p = q / (TR * TC), rem = q % (TR * TC);
        int r = rem / TC, c = rem % TC;
        int ih = reflect_i(oh0 + r - 3, H);
        int iw = reflect_i(ow0 + c - 3, W);
        s[p][r][c] = xn[(size_t)(ic0 + p) * H * W + (size_t)ih * W + iw];
    }
    __syncthreads();

    float acc[OCPT];
#pragma unroll
    for (int j = 0; j < OCPT; ++j) acc[j] = 0.f;

#pragma unroll
    for (int icl = 0; icl < ICPB; ++icl) {
        const float* wp = w + (size_t)(ic0 + icl) * 49;
#pragma unroll
        for (int kh = 0; kh < 7; ++kh) {
#pragma unroll
            for (int kw = 0; kw < 7; ++kw) {
                float vt = s[icl][ty + kh][tx + kw];
#pragma unroll
                for (int j = 0; j < OCPT; ++j)
                    acc[j] += vt * wp[(size_t)j * CINTOT * 49 + kh * 7 + kw];
            }
        }
    }

    int oh = oh0 + ty, ow = ow0 + tx;
    if (oh < H && ow < W) {
#pragma unroll
        for (int j = 0; j < OCPT; ++j)
            part[(size_t)ks * PS + (((size_t)n * OCPT + j) * H + oh) * W + ow] = acc[j];
    }
}

// ---------------- 3x3 s2 conv, float4 rows + f4 weights, fused stats --------
template <int CIN, int ICB, int OCPT>
__global__ __launch_bounds__(256) void conv3s2_f4(
    const float* __restrict__ x, const float* __restrict__ w,
    const float* __restrict__ b, float* __restrict__ y,
    float* __restrict__ spart, float* __restrict__ sspart, int P,
    int Cout, int Hin, int Win, int Hout, int Wout) {
    int tx = threadIdx.x & 15, ty = threadIdx.x >> 4;
    int tilesX = Wout >> 4;
    int ow = (blockIdx.x % tilesX) * 16 + tx;
    int oh = (blockIdx.x / tilesX) * 16 + ty;
    int oc0 = blockIdx.y * OCPT;
    int n = blockIdx.z;

    int iw0 = ow * 2 - 1;
    bool shb = iw0 < 0;                 // only ow==0 lanes
    int cb = shb ? 0 : iw0;             // clamped base col, in [0, Win-3]
    int ih0 = oh * 2 - 1;
    int rof[3];
    float mr[3];
#pragma unroll
    for (int kh = 0; kh < 3; ++kh) {
        int ih = ih0 + kh;
        int ihc = min(max(ih, 0), Hin - 1);
        rof[kh] = (ihc * Win + cb) * 4;
        mr[kh] = (ih >= 0 && ih < Hin) ? 1.f : 0.f;
    }

    float acc[OCPT];
#pragma unroll
    for (int j = 0; j < OCPT; ++j) acc[j] = 0.f;

    const char* xb = (const char*)x + (size_t)n * CIN * Hin * Win * 4;
    const int HWb = Hin * Win * 4;

    for (int ic0 = 0; ic0 < CIN; ic0 += ICB) {
        float t[ICB][9];
#pragma unroll
        for (int icl = 0; icl < ICB; ++icl) {
            const char* xp = xb + (size_t)(ic0 + icl) * HWb;  // uniform advance
#pragma unroll
            for (int kh = 0; kh < 3; ++kh) {
                float4 v = *(const float4*)(xp + rof[kh]);
                float e0 = shb ? 0.f : v.x;
                float e1 = shb ? v.x : v.y;
                float e2 = shb ? v.y : v.z;
                t[icl][kh * 3 + 0] = e0 * mr[kh];
                t[icl][kh * 3 + 1] = e1 * mr[kh];
                t[icl][kh * 3 + 2] = e2 * mr[kh];
            }
        }
#pragma unroll
        for (int icl = 0; icl < ICB; ++icl) {
            const float* wp = w + ((size_t)oc0 * CIN + ic0 + icl) * 9;
#pragma unroll
            for (int j = 0; j < OCPT; ++j) {
                const float* wj = wp + (size_t)j * CIN * 9;
                float4 wa = *(const float4*)wj;
                float4 wb = *(const float4*)(wj + 4);
                float w8 = wj[8];
                acc[j] += t[icl][0] * wa.x + t[icl][1] * wa.y + t[icl][2] * wa.z +
                          t[icl][3] * wa.w + t[icl][4] * wb.x + t[icl][5] * wb.y +
                          t[icl][6] * wb.z + t[icl][7] * wb.w + t[icl][8] * w8;
            }
        }
    }
    float sv[OCPT], ssv[OCPT];
#pragma unroll
    for (int j = 0; j < OCPT; ++j) {
        float r = acc[j] + b[oc0 + j];
        y[(((size_t)n * Cout + oc0 + j) * Hout + oh) * Wout + ow] = r;
        sv[j] = r;
        ssv[j] = r * r;
    }
    stats_block_store<OCPT>(sv, ssv, spart, sspart, P, blockIdx.x, n * Cout + oc0);
}

// ---------------- convT, 2 pixels/thread (qx, qx+16), shared weights --------
// Block covers 32 cols x 16 rows of input quads. Weights loaded once per
// (icl,j), used by BOTH pixels -> weight issue per output halves; 2
// independent load/FMA chains per wave for latency hiding. ICB=2 (VGPR cap).
template <int CIN, int ICB, int OCPT>
__global__ __launch_bounds__(256) void convt3_x2(
    const float* __restrict__ x, const float* __restrict__ w,
    const float* __restrict__ b, float* __restrict__ y,
    float* __restrict__ spart, float* __restrict__ sspart, int P,
    int Cout, int Hin, int Win, int Hout, int Wout) {
    int tx = threadIdx.x & 15, ty = threadIdx.x >> 4;
    int tilesX = IDIV(Win, 32);
    int bx = blockIdx.x % tilesX, by = blockIdx.x / tilesX;
    int qy = by * 16 + ty;
    int oc0 = blockIdx.y * OCPT;
    int n = blockIdx.z;

    int qxs[2];
    qxs[0] = bx * 32 + tx;
    qxs[1] = qxs[0] + 16;
    bool vldp[2], xinp[2], yinp[2];
    int p00[2], p10[2];
    float m01[2], m10[2], m11[2];
#pragma unroll
    for (int p = 0; p < 2; ++p) {
        bool valid = (qxs[p] < Win) && (qy < Hin);
        int qxc = min(qxs[p], Win - 1), qyc = min(qy, Hin - 1);
        bool xin = valid && (qxs[p] + 1 < Win);
        bool yin = valid && (qy + 1 < Hin);
        vldp[p] = valid; xinp[p] = xin; yinp[p] = yin;
        int o10 = yin ? Win : 0;
        m01[p] = xin ? 1.f : 0.f;
        m10[p] = yin ? 1.f : 0.f;
        m11[p] = m01[p] * m10[p];
        p00[p] = (qyc * Win + qxc) * 4;
        p10[p] = p00[p] + o10 * 4;
    }

    float a00[2][OCPT], a01[2][OCPT], a10[2][OCPT], a11[2][OCPT];
#pragma unroll
    for (int p = 0; p < 2; ++p)
#pragma unroll
        for (int j = 0; j < OCPT; ++j) {
            a00[p][j] = a01[p][j] = a10[p][j] = a11[p][j] = 0.f;
        }

    const char* xb = (const char*)x + (size_t)n * CIN * Hin * Win * 4;  // uniform
    const int HWb = Hin * Win * 4;

    float va[ICB][2][4], vb[ICB][2][4];
    auto load = [&](float (&v)[ICB][2][4], int ic0) {
#pragma unroll
        for (int icl = 0; icl < ICB; ++icl) {
            const char* xp = xb + (size_t)(ic0 + icl) * HWb;  // uniform advance
#pragma unroll
            for (int p = 0; p < 2; ++p) {
                float2 u = *(const float2*)(xp + p00[p]);
                float2 d = *(const float2*)(xp + p10[p]);
                v[icl][p][0] = u.x;
                v[icl][p][1] = u.y * m01[p];
                v[icl][p][2] = d.x * m10[p];
                v[icl][p][3] = d.y * m11[p];
            }
        }
    };
    auto fma = [&](const float (&v)[ICB][2][4], int ic0) {
#pragma unroll
        for (int icl = 0; icl < ICB; ++icl) {
            const float* wp = w + ((size_t)(ic0 + icl) * Cout + oc0) * 9;
#pragma unroll
            for (int j = 0; j < OCPT; ++j) {
                const float* wj = wp + j * 9;
                float4 wa = *(const float4*)wj;        // w0 w1 w2 w3
                float4 wb = *(const float4*)(wj + 4);  // w4 w5 w6 w7
                float w8 = wj[8];
#pragma unroll
                for (int p = 0; p < 2; ++p) {
                    a00[p][j] += wb.x * v[icl][p][0];
                    a01[p][j] += wb.y * v[icl][p][0] + wa.w * v[icl][p][1];
                    a10[p][j] += wb.w * v[icl][p][0] + wa.y * v[icl][p][2];
                    a11[p][j] += w8 * v[icl][p][0] + wb.z * v[icl][p][1] +
                                 wa.z * v[icl][p][2] + wa.x * v[icl][p][3];
                }
            }
        }
    };

    load(va, 0);
    for (int ic0 = 0; ic0 < CIN; ic0 += 2 * ICB) {
        load(vb, ic0 + ICB);
        fma(va, ic0);
        load(va, min(ic0 + 2 * ICB, CIN - ICB));
        fma(vb, ic0 + ICB);
    }

    int oh = 2 * qy;
    float sv[OCPT], ssv[OCPT];
#pragma unroll
    for (int j = 0; j < OCPT; ++j) {
        float s = 0.f, ss = 0.f;
        float bb = b[oc0 + j];
#pragma unroll
        for (int p = 0; p < 2; ++p) {
            if (vldp[p]) {
                int ow = 2 * qxs[p];
                float* yp = y + (((size_t)n * Cout + oc0 + j) * Hout + oh) * Wout + ow;
                float t00 = a00[p][j] + bb;
                yp[0] = t00; s += t00; ss += t00 * t00;
                if (xinp[p]) { float t = a01[p][j] + bb; yp[1] = t; s += t; ss += t * t; }
                if (yinp[p]) { float t = a10[p][j] + bb; yp[Wout] = t; s += t; ss += t * t; }
                if (xinp[p] && yinp[p]) {
                    float t = a11[p][j] + bb;
                    yp[Wout + 1] = t; s += t; ss += t * t;
                }
            }
        }
        sv[j] = s; ssv[j] = ss;
    }
    stats_block_store<OCPT>(sv, ssv, spart, sspart, P, blockIdx.x, n * Cout + oc0);
}

// ---------------- inorm apply, float4 coalesced (plane % 4 == 0) ------------
__global__ void inorm_apply4(float* __restrict__ x, const float* __restrict__ mean,
                             const float* __restrict__ inv, int plane4) {
    int pc = blockIdx.y;
    int i = blockIdx.x * 256 + threadIdx.x;
    if (i >= plane4) return;
    float m = mean[pc], iv = inv[pc];
    float4* p = (float4*)(x + (size_t)pc * plane4 * 4);
    float4 v = p[i];
    v.x = fmaxf(0.f, (v.x - m) * iv);
    v.y = fmaxf(0.f, (v.y - m) * iv);
    v.z = fmaxf(0.f, (v.z - m) * iv);
    v.w = fmaxf(0.f, (v.w - m) * iv);
    p[i] = v;
}

// ---------------- inorm apply, 1 elem/thread coalesced (any plane) ----------
__global__ void inorm_apply1(float* __restrict__ x, const float* __restrict__ mean,
                             const float* __restrict__ inv, int plane) {
    int pc = blockIdx.y;
    int i = blockIdx.x * 256 + threadIdx.x;
    if (i >= plane) return;
    float m = mean[pc], iv = inv[pc];
    size_t idx = (size_t)pc * plane + i;
    x[idx] = fmaxf(0.f, (x[idx] - m) * iv);
}

// ---------------- segment mean (accum fused with L7 finalize) ---------------
__global__ void seg_zero(float* __restrict__ bins) {
    if (threadIdx.x < 128) bins[threadIdx.x] = 0.f;
}

// reads the 4 ic-split partials + bias, computes tanh inline; a7 never built.
__global__ void seg_accum_f(const float* __restrict__ part, const float* __restrict__ b,
                            const int* __restrict__ inst, float* __restrict__ bins,
                            int HW, size_t PS) {
    __shared__ float ls[128];  // 96 sums + 32 counts
    for (int i = threadIdx.x; i < 128; i += 256) ls[i] = 0.f;
    __syncthreads();
    int n = blockIdx.y;
    int i = blockIdx.x * 256 + threadIdx.x;
    if (i < HW) {
        int id = inst[(size_t)n * HW + i];
#pragma unroll
        for (int c = 0; c < 3; ++c) {
            size_t off = ((size_t)(n * 3 + c)) * HW + i;
            float v = part[off] + part[PS + off] + part[2 * PS + off] +
                      part[3 * PS + off] + b[c];
            atomicAdd(&ls[id * 3 + c], tanhf(v));
        }
        atomicAdd(&ls[96 + id], 1.0f);
    }
    __syncthreads();
    for (int i2 = threadIdx.x; i2 < 128; i2 += 256)
        if (ls[i2] != 0.f) atomicAdd(&bins[i2], ls[i2]);
}

__global__ void seg_scatter(const float* __restrict__ bins, const int* __restrict__ inst,
                            float* __restrict__ out, int HW) {
    int n = blockIdx.y;
    int i = blockIdx.x * 256 + threadIdx.x;
    if (i >= HW) return;
    int id = inst[(size_t)n * HW + i];
    float c = fmaxf(bins[96 + id], 1.0f);
    out[((size_t)n * 3 + 0) * HW + i] = bins[id * 3 + 0] / c;
    out[((size_t)n * 3 + 1) * HW + i] = bins[id * 3 + 1] / c;
    out[((size_t)n * 3 + 2) * HW + i] = bins[id * 3 + 2] / c;
}

// ---------------------------------------------------------------------------
extern "C" void kernel_launch(void* const* d_in, const int* in_sizes, int n_in,
                              void* d_out, int out_size, void* d_ws, size_t ws_size,
                              hipStream_t stream) {
    const float* x = (const float*)d_in[0];
    const int* inst = (const int*)d_in[1];
    const float* W[8];
    const float* B[8];
    for (int i = 0; i < 8; ++i) {
        W[i] = (const float*)d_in[2 + 2 * i];
        B[i] = (const float*)d_in[3 + 2 * i];
    }
    float* ws = (float*)d_ws;

    // End-aligned ping-pong arena (R2/R6 proven)
    const size_t S = 25165824;  // floats
    float* a0 = ws;                  // [8,32,256,256]
    float* a1 = ws + 16777216;       // [8,64,128,128]
    float* a2 = ws;                  // [8,128,64,64]
    float* a3 = ws + 23068672;       // [8,256,32,32]
    float* a4 = ws;                  // [8,128,63,63]
    float* a5 = ws + 17165824;       // [8,64,125,125]
    float* a6 = ws;                  // [8,32,249,249]  0 .. 15.87M
    float* PART = ws + 16000000;     // 4 x 1488024 floats (gap above a6)
    float* mean = ws + S;            // 2048
    float* inv = mean + 2048;        // 2048
    float* bins = inv + 2048;        // 128
    float* spart = bins + 128;       // 65536 (max nT*P = 256*256)
    float* sspart = spart + 65536;   // 65536

    // L0: 7x7 reflect, 3->32, 256. LDS-staged, OCPT=8, 8192 blocks
    conv7_lds<3, 8><<<dim3(256, 4, 8), 256, 0, stream>>>(
        x, W[0], B[0], a0, spart, sspart, 256, 32, 256, 256);
    stat_reduce_mi<<<dim3(256), 64, 0, stream>>>(spart, sspart, mean, inv, 256, 256, 1.f / 65536.f);
    inorm_apply4<<<dim3(IDIV(16384, 256), 256), 256, 0, stream>>>(a0, mean, inv, 16384);

    // L1: 3x3 s2, 32->64, 256->128. float4 rows, ICB=2, OCPT=8, 4096 blocks
    conv3s2_f4<32, 2, 8><<<dim3(64, 8, 8), 256, 0, stream>>>(
        a0, W[1], B[1], a1, spart, sspart, 512, 64, 256, 256, 128, 128);
    stat_reduce_mi<<<dim3(512), 64, 0, stream>>>(spart, sspart, mean, inv, 512, 64, 1.f / 16384.f);
    inorm_apply4<<<dim3(IDIV(4096, 256), 512), 256, 0, stream>>>(a1, mean, inv, 4096);

    // L2: 3x3 s2, 64->128, 128->64. float4 rows, 2048 blocks
    conv3s2_f4<64, 2, 8><<<dim3(16, 16, 8), 256, 0, stream>>>(
        a1, W[2], B[2], a2, spart, sspart, 1024, 128, 128, 128, 64, 64);
    stat_reduce_mi<<<dim3(1024), 64, 0, stream>>>(spart, sspart, mean, inv, 1024, 16, 1.f / 4096.f);
    inorm_apply4<<<dim3(IDIV(1024, 256), 1024), 256, 0, stream>>>(a2, mean, inv, 1024);

    // L3: 3x3 s2, 128->256, 64->32. float4 rows, 1024 blocks
    conv3s2_f4<128, 2, 8><<<dim3(4, 32, 8), 256, 0, stream>>>(
        a2, W[3], B[3], a3, spart, sspart, 2048, 256, 64, 64, 32, 32);
    stat_reduce_mi<<<dim3(2048), 64, 0, stream>>>(spart, sspart, mean, inv, 2048, 4, 1.f / 1024.f);
    inorm_apply4<<<dim3(1, 2048), 256, 0, stream>>>(a3, mean, inv, 256);

    // L4: convT, 256->128, 32->63. 2px/thread, 512 blocks (2 tiles)
    convt3_x2<256, 2, 4><<<dim3(2, 32, 8), 256, 0, stream>>>(
        a3, W[4], B[4], a4, spart, sspart, 1024, 128, 32, 32, 63, 63);
    stat_reduce_mi<<<dim3(1024), 64, 0, stream>>>(spart, sspart, mean, inv, 1024, 2, 1.f / 3969.f);
    inorm_apply1<<<dim3(IDIV(3969, 256), 1024), 256, 0, stream>>>(a4, mean, inv, 3969);

    // L5: convT, 128->64, 63->125. 2px/thread, 1024 blocks (8 tiles)
    convt3_x2<128, 2, 4><<<dim3(8, 16, 8), 256, 0, stream>>>(
        a4, W[5], B[5], a5, spart, sspart, 512, 64, 63, 63, 125, 125);
    stat_reduce_mi<<<dim3(512), 64, 0, stream>>>(spart, sspart, mean, inv, 512, 8, 1.f / 15625.f);
    inorm_apply1<<<dim3(IDIV(15625, 256), 512), 256, 0, stream>>>(a5, mean, inv, 15625);

    // L6: convT, 64->32, 125->249. 2px/thread, 2048 blocks (32 tiles)
    convt3_x2<64, 2, 4><<<dim3(32, 8, 8), 256, 0, stream>>>(
        a5, W[6], B[6], a6, spart, sspart, 256, 32, 125, 125, 249, 249);
    stat_reduce_mi<<<dim3(256), 64, 0, stream>>>(spart, sspart, mean, inv, 256, 32, 1.f / 62001.f);
    inorm_apply1<<<dim3(IDIV(62001, 256), 256), 256, 0, stream>>>(a6, mean, inv, 62001);

    // L7: 7x7 reflect, 32->3, 249 — ic-split x4, LDS-staged
    conv7_part_lds<32, 8, 3><<<dim3(256, 4, 8), 256, 0, stream>>>(
        a6, W[7], PART, 1488024, 249, 249);

    // segment mean (accum reads partials + bias + tanh inline)
    seg_zero<<<1, 128, 0, stream>>>(bins);
    seg_accum_f<<<dim3(IDIV(62001, 256), 8), 256, 0, stream>>>(
        PART, B[7], inst, bins, 62001, 1488024);
    seg_scatter<<<dim3(IDIV(62001, 256), 8), 256, 0, stream>>>(bins, inst, (float*)d_out, 62001);
}

// Round 18
// 1159.709 us; speedup vs baseline: 1.3069x; 1.0067x over previous
//
#include <hip/hip_runtime.h>
#include <math.h>

// ---------------------------------------------------------------------------
// FeatureEncoder R36 = R35 RESUBMIT (previous round failed on container
// acquisition, not kernel fault — no compile error, no counters; code audit
// found no crash hazard: exact grids, arena-safe over-reads, R34-identical
// convT). Change under test remains: 2px/thread (shared weights) conv3s2
// L1-L3 — the chain-ILP mechanism proven on convT via 3 consecutive wins
// (1254->1216->1167us). Weight issue per output halves; 2 independent FMA
// chains per wave; coalescing preserved (pixel 2 = contiguous access at
// ow+16). Grids: L1 2048 blocks, L2 1024, L3 512 (occupancy-invariance
// proven R33/R34). stat nT: L1 32, L2 8, L3 2.
// convT/conv7/seg byte-identical to R34.
// ---------------------------------------------------------------------------

#define IDIV(a, b) (((a) + (b) - 1) / (b))

__device__ __forceinline__ int reflect_i(int i, int n) {
    i = i < 0 ? -i : i;
    return i >= n ? 2 * n - 2 - i : i;
}

__device__ __forceinline__ float ldb(const char* base, int boff) {
    return *(const float*)(base + boff);
}

// block-level (sum,sumsq) reduction for OCPT channels -> partial store
template <int OCPT>
__device__ __forceinline__ void stats_block_store(
    const float* sv, const float* ssv, float* __restrict__ spart,
    float* __restrict__ sspart, int P, int tile, int pc0) {
    __shared__ float redS[OCPT], redSS[OCPT];
    if (threadIdx.x < OCPT) { redS[threadIdx.x] = 0.f; redSS[threadIdx.x] = 0.f; }
    __syncthreads();
    int lane = threadIdx.x & 63;
#pragma unroll
    for (int j = 0; j < OCPT; ++j) {
        float s = sv[j], ss = ssv[j];
#pragma unroll
        for (int o = 32; o > 0; o >>= 1) {
            s += __shfl_down(s, o);
            ss += __shfl_down(ss, o);
        }
        if (lane == 0) { atomicAdd(&redS[j], s); atomicAdd(&redSS[j], ss); }  // LDS atomics
    }
    __syncthreads();
    if (threadIdx.x < OCPT) {
        spart[(size_t)tile * P + pc0 + threadIdx.x] = redS[threadIdx.x];
        sspart[(size_t)tile * P + pc0 + threadIdx.x] = redSS[threadIdx.x];
    }
}

// fold [nT][P] partials -> mean, inv (one wavefront per plane)
__global__ __launch_bounds__(64) void stat_reduce_mi(
    const float* __restrict__ sp, const float* __restrict__ ssp,
    float* __restrict__ mean, float* __restrict__ inv, int P, int nT,
    float rcp_plane) {
    int p = blockIdx.x;
    float a = 0.f, bsum = 0.f;
    for (int t = threadIdx.x; t < nT; t += 64) {
        a += sp[(size_t)t * P + p];
        bsum += ssp[(size_t)t * P + p];
    }
#pragma unroll
    for (int o = 32; o > 0; o >>= 1) {
        a += __shfl_down(a, o);
        bsum += __shfl_down(bsum, o);
    }
    if (threadIdx.x == 0) {
        float m = a * rcp_plane;
        float var = bsum * rcp_plane - m * m;
        mean[p] = m;
        inv[p] = rsqrtf(var + 1e-5f);
    }
}

// ---------------- 7x7 same-conv (L0), LDS-staged tile, fused stats ----------
template <int CIN, int OCPT>
__global__ __launch_bounds__(256) void conv7_lds(
    const float* __restrict__ x, const float* __restrict__ w,
    const float* __restrict__ b, float* __restrict__ y,
    float* __restrict__ spart, float* __restrict__ sspart, int P,
    int Cout, int H, int W) {
    constexpr int TR = 22, TC = 22, RS = 24;
    __shared__ float s[CIN][TR][RS];
    int tx = threadIdx.x & 15, ty = threadIdx.x >> 4;
    int tilesX = W / 16;
    int bx = blockIdx.x % tilesX, by = blockIdx.x / tilesX;
    int oh0 = by * 16, ow0 = bx * 16;
    int oc0 = blockIdx.y * OCPT;
    int n = blockIdx.z;
    const float* xn = x + (size_t)n * CIN * H * W;

    for (int q = threadIdx.x; q < CIN * TR * TC; q += 256) {
        int p = q / (TR * TC), rem = q % (TR * TC);
        int r = rem / TC, c = rem % TC;
        int ih = reflect_i(oh0 + r - 3, H);
        int iw = reflect_i(ow0 + c - 3, W);
        s[p][r][c] = xn[(size_t)p * H * W + (size_t)ih * W + iw];
    }
    __syncthreads();

    float acc[OCPT];
#pragma unroll
    for (int j = 0; j < OCPT; ++j) acc[j] = 0.f;

    for (int ic = 0; ic < CIN; ++ic) {
        const float* wp = w + ((size_t)oc0 * CIN + ic) * 49;
#pragma unroll
        for (int kh = 0; kh < 7; ++kh) {
#pragma unroll
            for (int kw = 0; kw < 7; ++kw) {
                float vt = s[ic][ty + kh][tx + kw];
#pragma unroll
                for (int j = 0; j < OCPT; ++j)
                    acc[j] += vt * wp[(size_t)j * CIN * 49 + kh * 7 + kw];
            }
        }
    }

    int oh = oh0 + ty, ow = ow0 + tx;
    float sv[OCPT], ssv[OCPT];
#pragma unroll
    for (int j = 0; j < OCPT; ++j) {
        float r = acc[j] + b[oc0 + j];
        y[(((size_t)n * Cout + oc0 + j) * H + oh) * W + ow] = r;
        sv[j] = r;
        ssv[j] = r * r;
    }
    stats_block_store<OCPT>(sv, ssv, spart, sspart, P, blockIdx.x, n * Cout + oc0);
}

// ---------------- 7x7 conv, ic-split partial (L7), LDS-staged ---------------
template <int CINTOT, int ICPB, int OCPT>
__global__ __launch_bounds__(256) void conv7_part_lds(
    const float* __restrict__ x, const float* __restrict__ w,
    float* __restrict__ part, size_t PS, int H, int W) {
    constexpr int TR = 22, TC = 22, RS = 24;
    __shared__ float s[ICPB][TR][RS];
    int tx = threadIdx.x & 15, ty = threadIdx.x >> 4;
    int tilesX = IDIV(W, 16);
    int bx = blockIdx.x % tilesX, by = blockIdx.x / tilesX;
    int oh0 = by * 16, ow0 = bx * 16;
    int ks = blockIdx.y;
    int n = blockIdx.z;
    const int ic0 = ks * ICPB;
    const float* xn = x + (size_t)n * CINTOT * H * W;

    for (int q = threadIdx.x; q < ICPB * TR * TC; q += 256) {
        int p = q / (TR * TC), rem = q % (TR * TC);
        int r = rem / TC, c = rem % TC;
        int ih = reflect_i(oh0 + r - 3, H);
        int iw = reflect_i(ow0 + c - 3, W);
        s[p][r][c] = xn[(size_t)(ic0 + p) * H * W + (size_t)ih * W + iw];
    }
    __syncthreads();

    float acc[OCPT];
#pragma unroll
    for (int j = 0; j < OCPT; ++j) acc[j] = 0.f;

#pragma unroll
    for (int icl = 0; icl < ICPB; ++icl) {
        const float* wp = w + (size_t)(ic0 + icl) * 49;
#pragma unroll
        for (int kh = 0; kh < 7; ++kh) {
#pragma unroll
            for (int kw = 0; kw < 7; ++kw) {
                float vt = s[icl][ty + kh][tx + kw];
#pragma unroll
                for (int j = 0; j < OCPT; ++j)
                    acc[j] += vt * wp[(size_t)j * CINTOT * 49 + kh * 7 + kw];
            }
        }
    }

    int oh = oh0 + ty, ow = ow0 + tx;
    if (oh < H && ow < W) {
#pragma unroll
        for (int j = 0; j < OCPT; ++j)
            part[(size_t)ks * PS + (((size_t)n * OCPT + j) * H + oh) * W + ow] = acc[j];
    }
}

// ---------------- 3x3 s2 conv, 2px/thread (ow, ow+16), shared weights -------
// Block covers 32 cols x 16 rows of outputs. Weight rows loaded once per
// (icl,j), FMA'd for both pixels. Input f4 rows per pixel stay coalesced.
// Requires Wout % 32 == 0 (exact grid).
template <int CIN, int ICB, int OCPT>
__global__ __launch_bounds__(256) void conv3s2_f4x2(
    const float* __restrict__ x, const float* __restrict__ w,
    const float* __restrict__ b, float* __restrict__ y,
    float* __restrict__ spart, float* __restrict__ sspart, int P,
    int Cout, int Hin, int Win, int Hout, int Wout) {
    int tx = threadIdx.x & 15, ty = threadIdx.x >> 4;
    int tilesX = Wout >> 5;
    int bx = blockIdx.x % tilesX, by = blockIdx.x / tilesX;
    int oh = by * 16 + ty;
    int oc0 = blockIdx.y * OCPT;
    int n = blockIdx.z;

    int ows[2];
    ows[0] = bx * 32 + tx;
    ows[1] = ows[0] + 16;

    int ih0 = oh * 2 - 1;
    float mr[3];
    int rbase[3];
#pragma unroll
    for (int kh = 0; kh < 3; ++kh) {
        int ih = ih0 + kh;
        int ihc = min(max(ih, 0), Hin - 1);
        rbase[kh] = ihc * Win;
        mr[kh] = (ih >= 0 && ih < Hin) ? 1.f : 0.f;
    }
    bool shbp[2];
    int rof[2][3];
#pragma unroll
    for (int p = 0; p < 2; ++p) {
        int iw0 = ows[p] * 2 - 1;
        bool shb = iw0 < 0;            // only possible for p==0, ow==0
        int cb = shb ? 0 : iw0;
        shbp[p] = shb;
#pragma unroll
        for (int kh = 0; kh < 3; ++kh) rof[p][kh] = (rbase[kh] + cb) * 4;
    }

    float acc[2][OCPT];
#pragma unroll
    for (int p = 0; p < 2; ++p)
#pragma unroll
        for (int j = 0; j < OCPT; ++j) acc[p][j] = 0.f;

    const char* xb = (const char*)x + (size_t)n * CIN * Hin * Win * 4;
    const int HWb = Hin * Win * 4;

    for (int ic0 = 0; ic0 < CIN; ic0 += ICB) {
        float t[ICB][2][9];
#pragma unroll
        for (int icl = 0; icl < ICB; ++icl) {
            const char* xp = xb + (size_t)(ic0 + icl) * HWb;  // uniform advance
#pragma unroll
            for (int p = 0; p < 2; ++p) {
#pragma unroll
                for (int kh = 0; kh < 3; ++kh) {
                    float4 v = *(const float4*)(xp + rof[p][kh]);
                    float e0 = shbp[p] ? 0.f : v.x;
                    float e1 = shbp[p] ? v.x : v.y;
                    float e2 = shbp[p] ? v.y : v.z;
                    t[icl][p][kh * 3 + 0] = e0 * mr[kh];
                    t[icl][p][kh * 3 + 1] = e1 * mr[kh];
                    t[icl][p][kh * 3 + 2] = e2 * mr[kh];
                }
            }
        }
#pragma unroll
        for (int icl = 0; icl < ICB; ++icl) {
            const float* wp = w + ((size_t)oc0 * CIN + ic0 + icl) * 9;
#pragma unroll
            for (int j = 0; j < OCPT; ++j) {
                const float* wj = wp + (size_t)j * CIN * 9;
                float4 wa = *(const float4*)wj;
                float4 wb = *(const float4*)(wj + 4);
                float w8 = wj[8];
#pragma unroll
                for (int p = 0; p < 2; ++p) {
                    acc[p][j] += t[icl][p][0] * wa.x + t[icl][p][1] * wa.y +
                                 t[icl][p][2] * wa.z + t[icl][p][3] * wa.w +
                                 t[icl][p][4] * wb.x + t[icl][p][5] * wb.y +
                                 t[icl][p][6] * wb.z + t[icl][p][7] * wb.w +
                                 t[icl][p][8] * w8;
                }
            }
        }
    }
    float sv[OCPT], ssv[OCPT];
#pragma unroll
    for (int j = 0; j < OCPT; ++j) {
        float bb = b[oc0 + j];
        float s = 0.f, ss = 0.f;
#pragma unroll
        for (int p = 0; p < 2; ++p) {
            float r = acc[p][j] + bb;
            y[(((size_t)n * Cout + oc0 + j) * Hout + oh) * Wout + ows[p]] = r;
            s += r; ss += r * r;
        }
        sv[j] = s; ssv[j] = ss;
    }
    stats_block_store<OCPT>(sv, ssv, spart, sspart, P, blockIdx.x, n * Cout + oc0);
}

// ---------------- convT, 2 pixels/thread (qx, qx+16), shared weights --------
template <int CIN, int ICB, int OCPT>
__global__ __launch_bounds__(256) void convt3_x2(
    const float* __restrict__ x, const float* __restrict__ w,
    const float* __restrict__ b, float* __restrict__ y,
    float* __restrict__ spart, float* __restrict__ sspart, int P,
    int Cout, int Hin, int Win, int Hout, int Wout) {
    int tx = threadIdx.x & 15, ty = threadIdx.x >> 4;
    int tilesX = IDIV(Win, 32);
    int bx = blockIdx.x % tilesX, by = blockIdx.x / tilesX;
    int qy = by * 16 + ty;
    int oc0 = blockIdx.y * OCPT;
    int n = blockIdx.z;

    int qxs[2];
    qxs[0] = bx * 32 + tx;
    qxs[1] = qxs[0] + 16;
    bool vldp[2], xinp[2], yinp[2];
    int p00[2], p10[2];
    float m01[2], m10[2], m11[2];
#pragma unroll
    for (int p = 0; p < 2; ++p) {
        bool valid = (qxs[p] < Win) && (qy < Hin);
        int qxc = min(qxs[p], Win - 1), qyc = min(qy, Hin - 1);
        bool xin = valid && (qxs[p] + 1 < Win);
        bool yin = valid && (qy + 1 < Hin);
        vldp[p] = valid; xinp[p] = xin; yinp[p] = yin;
        int o10 = yin ? Win : 0;
        m01[p] = xin ? 1.f : 0.f;
        m10[p] = yin ? 1.f : 0.f;
        m11[p] = m01[p] * m10[p];
        p00[p] = (qyc * Win + qxc) * 4;
        p10[p] = p00[p] + o10 * 4;
    }

    float a00[2][OCPT], a01[2][OCPT], a10[2][OCPT], a11[2][OCPT];
#pragma unroll
    for (int p = 0; p < 2; ++p)
#pragma unroll
        for (int j = 0; j < OCPT; ++j) {
            a00[p][j] = a01[p][j] = a10[p][j] = a11[p][j] = 0.f;
        }

    const char* xb = (const char*)x + (size_t)n * CIN * Hin * Win * 4;  // uniform
    const int HWb = Hin * Win * 4;

    float va[ICB][2][4], vb[ICB][2][4];
    auto load = [&](float (&v)[ICB][2][4], int ic0) {
#pragma unroll
        for (int icl = 0; icl < ICB; ++icl) {
            const char* xp = xb + (size_t)(ic0 + icl) * HWb;  // uniform advance
#pragma unroll
            for (int p = 0; p < 2; ++p) {
                float2 u = *(const float2*)(xp + p00[p]);
                float2 d = *(const float2*)(xp + p10[p]);
                v[icl][p][0] = u.x;
                v[icl][p][1] = u.y * m01[p];
                v[icl][p][2] = d.x * m10[p];
                v[icl][p][3] = d.y * m11[p];
            }
        }
    };
    auto fma = [&](const float (&v)[ICB][2][4], int ic0) {
#pragma unroll
        for (int icl = 0; icl < ICB; ++icl) {
            const float* wp = w + ((size_t)(ic0 + icl) * Cout + oc0) * 9;
#pragma unroll
            for (int j = 0; j < OCPT; ++j) {
                const float* wj = wp + j * 9;
                float4 wa = *(const float4*)wj;        // w0 w1 w2 w3
                float4 wb = *(const float4*)(wj + 4);  // w4 w5 w6 w7
                float w8 = wj[8];
#pragma unroll
                for (int p = 0; p < 2; ++p) {
                    a00[p][j] += wb.x * v[icl][p][0];
                    a01[p][j] += wb.y * v[icl][p][0] + wa.w * v[icl][p][1];
                    a10[p][j] += wb.w * v[icl][p][0] + wa.y * v[icl][p][2];
                    a11[p][j] += w8 * v[icl][p][0] + wb.z * v[icl][p][1] +
                                 wa.z * v[icl][p][2] + wa.x * v[icl][p][3];
                }
            }
        }
    };

    load(va, 0);
    for (int ic0 = 0; ic0 < CIN; ic0 += 2 * ICB) {
        load(vb, ic0 + ICB);
        fma(va, ic0);
        load(va, min(ic0 + 2 * ICB, CIN - ICB));
        fma(vb, ic0 + ICB);
    }

    int oh = 2 * qy;
    float sv[OCPT], ssv[OCPT];
#pragma unroll
    for (int j = 0; j < OCPT; ++j) {
        float s = 0.f, ss = 0.f;
        float bb = b[oc0 + j];
#pragma unroll
        for (int p = 0; p < 2; ++p) {
            if (vldp[p]) {
                int ow = 2 * qxs[p];
                float* yp = y + (((size_t)n * Cout + oc0 + j) * Hout + oh) * Wout + ow;
                float t00 = a00[p][j] + bb;
                yp[0] = t00; s += t00; ss += t00 * t00;
                if (xinp[p]) { float t = a01[p][j] + bb; yp[1] = t; s += t; ss += t * t; }
                if (yinp[p]) { float t = a10[p][j] + bb; yp[Wout] = t; s += t; ss += t * t; }
                if (xinp[p] && yinp[p]) {
                    float t = a11[p][j] + bb;
                    yp[Wout + 1] = t; s += t; ss += t * t;
                }
            }
        }
        sv[j] = s; ssv[j] = ss;
    }
    stats_block_store<OCPT>(sv, ssv, spart, sspart, P, blockIdx.x, n * Cout + oc0);
}

// ---------------- inorm apply, float4 coalesced (plane % 4 == 0) ------------
__global__ void inorm_apply4(float* __restrict__ x, const float* __restrict__ mean,
                             const float* __restrict__ inv, int plane4) {
    int pc = blockIdx.y;
    int i = blockIdx.x * 256 + threadIdx.x;
    if (i >= plane4) return;
    float m = mean[pc], iv = inv[pc];
    float4* p = (float4*)(x + (size_t)pc * plane4 * 4);
    float4 v = p[i];
    v.x = fmaxf(0.f, (v.x - m) * iv);
    v.y = fmaxf(0.f, (v.y - m) * iv);
    v.z = fmaxf(0.f, (v.z - m) * iv);
    v.w = fmaxf(0.f, (v.w - m) * iv);
    p[i] = v;
}

// ---------------- inorm apply, 1 elem/thread coalesced (any plane) ----------
__global__ void inorm_apply1(float* __restrict__ x, const float* __restrict__ mean,
                             const float* __restrict__ inv, int plane) {
    int pc = blockIdx.y;
    int i = blockIdx.x * 256 + threadIdx.x;
    if (i >= plane) return;
    float m = mean[pc], iv = inv[pc];
    size_t idx = (size_t)pc * plane + i;
    x[idx] = fmaxf(0.f, (x[idx] - m) * iv);
}

// ---------------- segment mean (accum fused with L7 finalize) ---------------
__global__ void seg_zero(float* __restrict__ bins) {
    if (threadIdx.x < 128) bins[threadIdx.x] = 0.f;
}

// reads the 4 ic-split partials + bias, computes tanh inline; a7 never built.
__global__ void seg_accum_f(const float* __restrict__ part, const float* __restrict__ b,
                            const int* __restrict__ inst, float* __restrict__ bins,
                            int HW, size_t PS) {
    __shared__ float ls[128];  // 96 sums + 32 counts
    for (int i = threadIdx.x; i < 128; i += 256) ls[i] = 0.f;
    __syncthreads();
    int n = blockIdx.y;
    int i = blockIdx.x * 256 + threadIdx.x;
    if (i < HW) {
        int id = inst[(size_t)n * HW + i];
#pragma unroll
        for (int c = 0; c < 3; ++c) {
            size_t off = ((size_t)(n * 3 + c)) * HW + i;
            float v = part[off] + part[PS + off] + part[2 * PS + off] +
                      part[3 * PS + off] + b[c];
            atomicAdd(&ls[id * 3 + c], tanhf(v));
        }
        atomicAdd(&ls[96 + id], 1.0f);
    }
    __syncthreads();
    for (int i2 = threadIdx.x; i2 < 128; i2 += 256)
        if (ls[i2] != 0.f) atomicAdd(&bins[i2], ls[i2]);
}

__global__ void seg_scatter(const float* __restrict__ bins, const int* __restrict__ inst,
                            float* __restrict__ out, int HW) {
    int n = blockIdx.y;
    int i = blockIdx.x * 256 + threadIdx.x;
    if (i >= HW) return;
    int id = inst[(size_t)n * HW + i];
    float c = fmaxf(bins[96 + id], 1.0f);
    out[((size_t)n * 3 + 0) * HW + i] = bins[id * 3 + 0] / c;
    out[((size_t)n * 3 + 1) * HW + i] = bins[id * 3 + 1] / c;
    out[((size_t)n * 3 + 2) * HW + i] = bins[id * 3 + 2] / c;
}

// ---------------------------------------------------------------------------
extern "C" void kernel_launch(void* const* d_in, const int* in_sizes, int n_in,
                              void* d_out, int out_size, void* d_ws, size_t ws_size,
                              hipStream_t stream) {
    const float* x = (const float*)d_in[0];
    const int* inst = (const int*)d_in[1];
    const float* W[8];
    const float* B[8];
    for (int i = 0; i < 8; ++i) {
        W[i] = (const float*)d_in[2 + 2 * i];
        B[i] = (const float*)d_in[3 + 2 * i];
    }
    float* ws = (float*)d_ws;

    // End-aligned ping-pong arena (R2/R6 proven)
    const size_t S = 25165824;  // floats
    float* a0 = ws;                  // [8,32,256,256]
    float* a1 = ws + 16777216;       // [8,64,128,128]
    float* a2 = ws;                  // [8,128,64,64]
    float* a3 = ws + 23068672;       // [8,256,32,32]
    float* a4 = ws;                  // [8,128,63,63]
    float* a5 = ws + 17165824;       // [8,64,125,125]
    float* a6 = ws;                  // [8,32,249,249]  0 .. 15.87M
    float* PART = ws + 16000000;     // 4 x 1488024 floats (gap above a6)
    float* mean = ws + S;            // 2048
    float* inv = mean + 2048;        // 2048
    float* bins = inv + 2048;        // 128
    float* spart = bins + 128;       // 65536 (max nT*P = 256*256)
    float* sspart = spart + 65536;   // 65536

    // L0: 7x7 reflect, 3->32, 256. LDS-staged, OCPT=8, 8192 blocks
    conv7_lds<3, 8><<<dim3(256, 4, 8), 256, 0, stream>>>(
        x, W[0], B[0], a0, spart, sspart, 256, 32, 256, 256);
    stat_reduce_mi<<<dim3(256), 64, 0, stream>>>(spart, sspart, mean, inv, 256, 256, 1.f / 65536.f);
    inorm_apply4<<<dim3(IDIV(16384, 256), 256), 256, 0, stream>>>(a0, mean, inv, 16384);

    // L1: 3x3 s2, 32->64, 256->128. 2px/thread, 2048 blocks (32 tiles)
    conv3s2_f4x2<32, 2, 8><<<dim3(32, 8, 8), 256, 0, stream>>>(
        a0, W[1], B[1], a1, spart, sspart, 512, 64, 256, 256, 128, 128);
    stat_reduce_mi<<<dim3(512), 64, 0, stream>>>(spart, sspart, mean, inv, 512, 32, 1.f / 16384.f);
    inorm_apply4<<<dim3(IDIV(4096, 256), 512), 256, 0, stream>>>(a1, mean, inv, 4096);

    // L2: 3x3 s2, 64->128, 128->64. 2px/thread, 1024 blocks (8 tiles)
    conv3s2_f4x2<64, 2, 8><<<dim3(8, 16, 8), 256, 0, stream>>>(
        a1, W[2], B[2], a2, spart, sspart, 1024, 128, 128, 128, 64, 64);
    stat_reduce_mi<<<dim3(1024), 64, 0, stream>>>(spart, sspart, mean, inv, 1024, 8, 1.f / 4096.f);
    inorm_apply4<<<dim3(IDIV(1024, 256), 1024), 256, 0, stream>>>(a2, mean, inv, 1024);

    // L3: 3x3 s2, 128->256, 64->32. 2px/thread, 512 blocks (2 tiles)
    conv3s2_f4x2<128, 2, 8><<<dim3(2, 32, 8), 256, 0, stream>>>(
        a2, W[3], B[3], a3, spart, sspart, 2048, 256, 64, 64, 32, 32);
    stat_reduce_mi<<<dim3(2048), 64, 0, stream>>>(spart, sspart, mean, inv, 2048, 2, 1.f / 1024.f);
    inorm_apply4<<<dim3(1, 2048), 256, 0, stream>>>(a3, mean, inv, 256);

    // L4: convT, 256->128, 32->63. 2px/thread, 512 blocks (2 tiles)
    convt3_x2<256, 2, 4><<<dim3(2, 32, 8), 256, 0, stream>>>(
        a3, W[4], B[4], a4, spart, sspart, 1024, 128, 32, 32, 63, 63);
    stat_reduce_mi<<<dim3(1024), 64, 0, stream>>>(spart, sspart, mean, inv, 1024, 2, 1.f / 3969.f);
    inorm_apply1<<<dim3(IDIV(3969, 256), 1024), 256, 0, stream>>>(a4, mean, inv, 3969);

    // L5: convT, 128->64, 63->125. 2px/thread, 1024 blocks (8 tiles)
    convt3_x2<128, 2, 4><<<dim3(8, 16, 8), 256, 0, stream>>>(
        a4, W[5], B[5], a5, spart, sspart, 512, 64, 63, 63, 125, 125);
    stat_reduce_mi<<<dim3(512), 64, 0, stream>>>(spart, sspart, mean, inv, 512, 8, 1.f / 15625.f);
    inorm_apply1<<<dim3(IDIV(15625, 256), 512), 256, 0, stream>>>(a5, mean, inv, 15625);

    // L6: convT, 64->32, 125->249. 2px/thread, 2048 blocks (32 tiles)
    convt3_x2<64, 2, 4><<<dim3(32, 8, 8), 256, 0, stream>>>(
        a5, W[6], B[6], a6, spart, sspart, 256, 32, 125, 125, 249, 249);
    stat_reduce_mi<<<dim3(256), 64, 0, stream>>>(spart, sspart, mean, inv, 256, 32, 1.f / 62001.f);
    inorm_apply1<<<dim3(IDIV(62001, 256), 256), 256, 0, stream>>>(a6, mean, inv, 62001);

    // L7: 7x7 reflect, 32->3, 249 — ic-split x4, LDS-staged
    conv7_part_lds<32, 8, 3><<<dim3(256, 4, 8), 256, 0, stream>>>(
        a6, W[7], PART, 1488024, 249, 249);

    // segment mean (accum reads partials + bias + tanh inline)
    seg_zero<<<1, 128, 0, stream>>>(bins);
    seg_accum_f<<<dim3(IDIV(62001, 256), 8), 256, 0, stream>>>(
        PART, B[7], inst, bins, 62001, 1488024);
    seg_scatter<<<dim3(IDIV(62001, 256), 8), 256, 0, stream>>>(bins, inst, (float*)d_out, 62001);
}